// Round 1
// 6566.234 us; speedup vs baseline: 1.0726x; 1.0726x over previous
//
#include <hip/hip_runtime.h>
#include <cstdint>
#include <cstddef>

typedef unsigned short u16;
typedef unsigned int   u32;
typedef _Float16       f16;

typedef float f32x4 __attribute__((ext_vector_type(4)));
typedef _Float16 f16x8 __attribute__((ext_vector_type(8)));

#define MB (1024u*1024u)
#define RCP2048 (1.0f/2048.0f)

__device__ __forceinline__ float gelu_f(float u) {
    return 0.5f * u * (1.0f + erff(u * 0.70710678118654752f));
}

__device__ __forceinline__ void split_f(float v, f16* hi, f16* lo) {
    f16 h = (f16)v;
    *hi = h;
    *lo = (f16)((v - (float)h) * 2048.0f);
}

__device__ __forceinline__ void gload_lds16(const f16* g, f16* l) {
    __builtin_amdgcn_global_load_lds((const __attribute__((address_space(1))) u32*)(g),
                                     (__attribute__((address_space(3))) u32*)(l), 16, 0, 0);
}

// ---------------- transpose + split: in [R][C] f32 -> hi/lo fp16 [C][R] ----------------
__global__ void transpose_split_k(const float* __restrict__ in, f16* __restrict__ oh, f16* __restrict__ ol,
                                  int R, int C, long bsi, long bso) {
    __shared__ float tile[32][33];
    int z = blockIdx.z;
    in += (size_t)z * bsi; oh += (size_t)z * bso; ol += (size_t)z * bso;
    int c0 = blockIdx.x * 32, r0 = blockIdx.y * 32;
    int tx = threadIdx.x, ty = threadIdx.y;   // (32,8)
#pragma unroll
    for (int i = 0; i < 4; i++)
        tile[ty + i*8][tx] = in[(size_t)(r0 + ty + i*8) * C + c0 + tx];
    __syncthreads();
#pragma unroll
    for (int i = 0; i < 4; i++) {
        float v = tile[tx][ty + i*8];
        f16 h, l; split_f(v, &h, &l);
        size_t o = (size_t)(c0 + ty + i*8) * R + r0 + tx;
        oh[o] = h; ol[o] = l;
    }
}

// ---------------- f16 plane transpose (for V): src[t][1536] col-block -> vt[bh][d][n] ----------------
__global__ void transpose_v_k(const f16* __restrict__ plane, f16* __restrict__ vt) {
    __shared__ f16 tile[32][33];
    int bh = blockIdx.z; int b = bh >> 3, h = bh & 7;
    int n0 = blockIdx.x * 32, d0 = blockIdx.y * 32;
    int tx = threadIdx.x, ty = threadIdx.y;   // (32,8)
    const f16* src = plane + (size_t)b * 1024 * 1536 + 1024 + h * 64;
#pragma unroll
    for (int i = 0; i < 4; i++)
        tile[ty + i*8][tx] = src[(size_t)(n0 + ty + i*8) * 1536 + d0 + tx];
    __syncthreads();
    f16* dst = vt + (size_t)bh * 64 * 1024;
#pragma unroll
    for (int i = 0; i < 4; i++)
        dst[(size_t)(d0 + ty + i*8) * 1024 + n0 + tx] = tile[tx][ty + i*8];
}

// ---------------- LayerNorm: fp32 in -> optional fp32 out + hi/lo fp16 planes ----------------
template<int W32>
__global__ __launch_bounds__(256) void ln_split_k(const float* __restrict__ x, const float* __restrict__ w,
                                                  const float* __restrict__ b, float* __restrict__ o32,
                                                  f16* __restrict__ oh, f16* __restrict__ ol) {
    int t = blockIdx.x, tid = threadIdx.x;
    const float* xr = x + (size_t)t * 512;
    float v0 = xr[tid], v1 = xr[tid + 256];
    float s = v0 + v1, ss = v0*v0 + v1*v1;
#pragma unroll
    for (int m = 32; m; m >>= 1) { s += __shfl_xor(s, m); ss += __shfl_xor(ss, m); }
    __shared__ float red[8];
    int wv = tid >> 6;
    if ((tid & 63) == 0) { red[wv] = s; red[4 + wv] = ss; }
    __syncthreads();
    s  = red[0] + red[1] + red[2] + red[3];
    ss = red[4] + red[5] + red[6] + red[7];
    float mean = s * (1.f/512.f);
    float var  = ss * (1.f/512.f) - mean * mean;
    float rstd = rsqrtf(var + 1e-5f);
    float u0 = (v0 - mean) * rstd * w[tid]       + b[tid];
    float u1 = (v1 - mean) * rstd * w[tid + 256] + b[tid + 256];
    size_t base = (size_t)t * 512;
    if (W32) { o32[base + tid] = u0; o32[base + tid + 256] = u1; }
    f16 h0, l0, h1, l1;
    split_f(u0, &h0, &l0); split_f(u1, &h1, &l1);
    oh[base + tid] = h0; ol[base + tid] = l0;
    oh[base + tid + 256] = h1; ol[base + tid + 256] = l1;
}

// ---------------- plain fp32 LayerNorm (final) ----------------
__global__ __launch_bounds__(256) void ln_k(const float* __restrict__ x, const float* __restrict__ w,
                                            const float* __restrict__ b, float* __restrict__ out) {
    int t = blockIdx.x, tid = threadIdx.x;
    const float* xr = x + (size_t)t * 512;
    float v0 = xr[tid], v1 = xr[tid + 256];
    float s = v0 + v1, ss = v0*v0 + v1*v1;
#pragma unroll
    for (int m = 32; m; m >>= 1) { s += __shfl_xor(s, m); ss += __shfl_xor(ss, m); }
    __shared__ float red[8];
    int wv = tid >> 6;
    if ((tid & 63) == 0) { red[wv] = s; red[4 + wv] = ss; }
    __syncthreads();
    s  = red[0] + red[1] + red[2] + red[3];
    ss = red[4] + red[5] + red[6] + red[7];
    float mean = s * (1.f/512.f);
    float var  = ss * (1.f/512.f) - mean * mean;
    float rstd = rsqrtf(var + 1e-5f);
    out[(size_t)t*512 + tid]       = (v0 - mean) * rstd * w[tid]       + b[tid];
    out[(size_t)t*512 + tid + 256] = (v1 - mean) * rstd * w[tid + 256] + b[tid + 256];
}

// ---------------- split-fp16 MFMA GEMM: C = (Ah+Al/2048) @ (Bh+Bl/2048)^T ----------------
// A[M,K] hi/lo, Bt[N,K] hi/lo. 128x128 tile, BK=32, 3 MFMA products.
// EPI: 0 = split-store fp16 hi/lo; 1 = fp32 C += acc + bias; 2 = gelu(acc+bias) split-store;
//      3 = fp32 C = acc + bias; 4 = fp32 C += acc
template<int EPI>
__global__ __launch_bounds__(256) void gemm_sp(
    const f16* __restrict__ Ah, const f16* __restrict__ Al, int lda,
    const f16* __restrict__ Bh, const f16* __restrict__ Bl, int ldb,
    const float* __restrict__ bias,
    void* __restrict__ C0v, void* __restrict__ C1v, int ldc,
    int M, int K,
    const int* __restrict__ cnts, const int* __restrict__ offs,
    long bStrideZ, long biasStrideZ)
{
    int e = blockIdx.z;
    int mcnt = M;
    long aoff = 0;
    if (cnts) {
        mcnt = cnts[e];
        if ((int)(blockIdx.x * 128) >= mcnt) return;
        aoff = offs[e];
        Ah += (size_t)aoff * lda; Al += (size_t)aoff * lda;
        Bh += (size_t)e * bStrideZ; Bl += (size_t)e * bStrideZ;
        if (bias) bias += (size_t)e * biasStrideZ;
    } else if ((int)(blockIdx.x * 128) >= mcnt) return;

    f16*   C0h = (f16*)C0v   + (size_t)aoff * ldc;
    f16*   C1l = (f16*)C1v   + (size_t)aoff * ldc;
    float* Cf  = (float*)C0v + (size_t)aoff * ldc;

    const int m0 = blockIdx.x * 128, n0 = blockIdx.y * 128;
    const int tid  = threadIdx.x;
    const int wave = tid >> 6, lane = tid & 63;
    const int quad = lane >> 4, l15 = lane & 15;
    const int wr = (wave >> 1) * 64, wc = (wave & 1) * 64;

    __shared__ __align__(16) f16 Ash[4096];
    __shared__ __align__(16) f16 Asl[4096];
    __shared__ __align__(16) f16 Bsh[4096];
    __shared__ __align__(16) f16 Bsl[4096];

    f32x4 acc[4][4] = {};
    f32x4 ac2[4][4] = {};

    const int la = tid * 8;
    const int ra = tid >> 2, ca = (tid & 3) * 8;
    int r0a = m0 + ra;        if (r0a > mcnt - 1) r0a = mcnt - 1;
    int r1a = m0 + ra + 64;   if (r1a > mcnt - 1) r1a = mcnt - 1;
    const f16* ah0 = Ah + (size_t)r0a * lda + ca;
    const f16* ah1 = Ah + (size_t)r1a * lda + ca;
    const f16* al0 = Al + (size_t)r0a * lda + ca;
    const f16* al1 = Al + (size_t)r1a * lda + ca;
    const f16* bh0 = Bh + (size_t)(n0 + ra) * ldb + ca;
    const f16* bh1 = Bh + (size_t)(n0 + ra + 64) * ldb + ca;
    const f16* bl0 = Bl + (size_t)(n0 + ra) * ldb + ca;
    const f16* bl1 = Bl + (size_t)(n0 + ra + 64) * ldb + ca;

    for (int k0 = 0; k0 < K; k0 += 32) {
        __syncthreads();
        gload_lds16(ah0 + k0, &Ash[la]);
        gload_lds16(ah1 + k0, &Ash[2048 + la]);
        gload_lds16(al0 + k0, &Asl[la]);
        gload_lds16(al1 + k0, &Asl[2048 + la]);
        gload_lds16(bh0 + k0, &Bsh[la]);
        gload_lds16(bh1 + k0, &Bsh[2048 + la]);
        gload_lds16(bl0 + k0, &Bsl[la]);
        gload_lds16(bl1 + k0, &Bsl[2048 + la]);
        __syncthreads();
        f16x8 afh[4], afl[4], bfh[4], bfl[4];
#pragma unroll
        for (int mi = 0; mi < 4; mi++) {
            int ro = (wr + mi*16 + l15) * 32 + quad * 8;
            afh[mi] = *(const f16x8*)&Ash[ro];
            afl[mi] = *(const f16x8*)&Asl[ro];
        }
#pragma unroll
        for (int ni = 0; ni < 4; ni++) {
            int ro = (wc + ni*16 + l15) * 32 + quad * 8;
            bfh[ni] = *(const f16x8*)&Bsh[ro];
            bfl[ni] = *(const f16x8*)&Bsl[ro];
        }
#pragma unroll
        for (int mi = 0; mi < 4; mi++)
#pragma unroll
            for (int ni = 0; ni < 4; ni++) {
                acc[mi][ni] = __builtin_amdgcn_mfma_f32_16x16x32_f16(afh[mi], bfh[ni], acc[mi][ni], 0, 0, 0);
                ac2[mi][ni] = __builtin_amdgcn_mfma_f32_16x16x32_f16(afh[mi], bfl[ni], ac2[mi][ni], 0, 0, 0);
                ac2[mi][ni] = __builtin_amdgcn_mfma_f32_16x16x32_f16(afl[mi], bfh[ni], ac2[mi][ni], 0, 0, 0);
            }
    }

#pragma unroll
    for (int mi = 0; mi < 4; mi++) {
#pragma unroll
        for (int r = 0; r < 4; r++) {
            int row = m0 + wr + mi*16 + quad*4 + r;
            if (row >= mcnt) continue;
            size_t ro = (size_t)row * ldc;
#pragma unroll
            for (int ni = 0; ni < 4; ni++) {
                int col = n0 + wc + ni*16 + l15;
                float v = acc[mi][ni][r] + ac2[mi][ni][r] * RCP2048;
                if (EPI == 0) {
                    f16 h, l; split_f(v, &h, &l);
                    C0h[ro + col] = h; C1l[ro + col] = l;
                } else if (EPI == 1) {
                    Cf[ro + col] += v + bias[col];
                } else if (EPI == 2) {
                    float g = gelu_f(v + bias[col]);
                    f16 h, l; split_f(g, &h, &l);
                    C0h[ro + col] = h; C1l[ro + col] = l;
                } else if (EPI == 3) {
                    Cf[ro + col] = v + bias[col];
                } else {
                    Cf[ro + col] += v;
                }
            }
        }
    }
}

// ---------------- split-fp16 flash attention: grid (16 q-tiles, 64 bh), block 256 ----------------
// K/V tiles staged once per BLOCK into LDS via global_load_lds (4 waves share the same bh),
// XOR-swizzled via the global source address (linear LDS dest): slot' = slot ^ (row&7).
// This removes the 4x duplicated per-wave L2/L3 streaming of K/V (was ~2 GB/dispatch).
__global__ __launch_bounds__(256) void attn_sp(const f16* __restrict__ qh, const f16* __restrict__ ql,
                                               const f16* __restrict__ vth, const f16* __restrict__ vtl,
                                               f16* __restrict__ oh, f16* __restrict__ ol) {
    const int qt = blockIdx.x;
    const int bh = blockIdx.y;
    const int b = bh >> 3, h = bh & 7;
    const int tid = threadIdx.x;
    const int wave = tid >> 6, lane = tid & 63;
    const int quad = lane >> 4, l15 = lane & 15;

    __shared__ __align__(16) f16 Ksh[4096];   // [64 kv][64 d] hi, swizzled
    __shared__ __align__(16) f16 Ksl[4096];   // lo
    __shared__ __align__(16) f16 Vsh[4096];   // [64 d][64 kv] hi, swizzled
    __shared__ __align__(16) f16 Vsl[4096];   // lo
    __shared__ __align__(16) f16 Ph[4][16][80];
    __shared__ __align__(16) f16 Pl[4][16][80];

    const size_t tq = (size_t)b * 1024 + qt * 64 + wave * 16 + l15;
    f16x8 qh0 = *(const f16x8*)&qh[tq * 1536 + h * 64 + quad * 8];
    f16x8 qh1 = *(const f16x8*)&qh[tq * 1536 + h * 64 + 32 + quad * 8];
    f16x8 ql0 = *(const f16x8*)&ql[tq * 1536 + h * 64 + quad * 8];
    f16x8 ql1 = *(const f16x8*)&ql[tq * 1536 + h * 64 + 32 + quad * 8];

    f32x4 ao[4] = {}, ao2[4] = {};
    float m_i[4] = {-INFINITY, -INFINITY, -INFINITY, -INFINITY};
    float l_i[4] = {0.f, 0.f, 0.f, 0.f};

    const f16* kbh = qh + (size_t)b * 1024 * 1536 + 512 + h * 64;
    const f16* kbl = ql + (size_t)b * 1024 * 1536 + 512 + h * 64;
    const f16* vbh = vth + (size_t)bh * 64 * 1024;
    const f16* vbl = vtl + (size_t)bh * 64 * 1024;

    // staging geometry: 512 chunks of 16B per 8KB tile; this thread owns chunks tid and tid+256.
    // chunk c -> LDS f16 offset c*8 (linear); holds global slot (c&7)^(row&7) of row c>>3.
    const int c0 = tid,       r0 = c0 >> 3, g0 = ((c0 & 7) ^ (r0 & 7)) * 8;
    const int c1 = tid + 256, r1 = c1 >> 3, g1 = ((c1 & 7) ^ (r1 & 7)) * 8;
    const int ko0 = r0 * 1536 + g0, ko1 = r1 * 1536 + g1;   // K: row stride 1536 f16
    const int vo0 = r0 * 1024 + g0, vo1 = r1 * 1024 + g1;   // V^T: row stride 1024 f16

    for (int kv0 = 0; kv0 < 1024; kv0 += 64) {
        __syncthreads();   // previous iteration's LDS reads complete before overwrite
        {
            const size_t kadv = (size_t)kv0 * 1536;
            gload_lds16(kbh + kadv + ko0, &Ksh[c0 * 8]);
            gload_lds16(kbh + kadv + ko1, &Ksh[c1 * 8]);
            gload_lds16(kbl + kadv + ko0, &Ksl[c0 * 8]);
            gload_lds16(kbl + kadv + ko1, &Ksl[c1 * 8]);
            gload_lds16(vbh + kv0 + vo0, &Vsh[c0 * 8]);
            gload_lds16(vbh + kv0 + vo1, &Vsh[c1 * 8]);
            gload_lds16(vbl + kv0 + vo0, &Vsl[c0 * 8]);
            gload_lds16(vbl + kv0 + vo1, &Vsl[c1 * 8]);
        }
        __syncthreads();   // drains vmcnt(0): tiles landed for all waves

        f32x4 sa[4] = {}, sa2[4] = {};
        const int sw = l15 & 7;
#pragma unroll
        for (int ni = 0; ni < 4; ni++) {
            const int kb = (ni*16 + l15) * 64;
            f16x8 kh0 = *(const f16x8*)&Ksh[kb + ((quad       ^ sw) << 3)];
            f16x8 kh1 = *(const f16x8*)&Ksh[kb + (((quad + 4) ^ sw) << 3)];
            f16x8 kl0 = *(const f16x8*)&Ksl[kb + ((quad       ^ sw) << 3)];
            f16x8 kl1 = *(const f16x8*)&Ksl[kb + (((quad + 4) ^ sw) << 3)];
            sa[ni]  = __builtin_amdgcn_mfma_f32_16x16x32_f16(qh0, kh0, sa[ni], 0, 0, 0);
            sa[ni]  = __builtin_amdgcn_mfma_f32_16x16x32_f16(qh1, kh1, sa[ni], 0, 0, 0);
            sa2[ni] = __builtin_amdgcn_mfma_f32_16x16x32_f16(qh0, kl0, sa2[ni], 0, 0, 0);
            sa2[ni] = __builtin_amdgcn_mfma_f32_16x16x32_f16(qh1, kl1, sa2[ni], 0, 0, 0);
            sa2[ni] = __builtin_amdgcn_mfma_f32_16x16x32_f16(ql0, kh0, sa2[ni], 0, 0, 0);
            sa2[ni] = __builtin_amdgcn_mfma_f32_16x16x32_f16(ql1, kh1, sa2[ni], 0, 0, 0);
        }
        float alpha[4];
#pragma unroll
        for (int r = 0; r < 4; r++) {
            float s0 = (sa[0][r] + sa2[0][r]*RCP2048) * 0.125f;
            float s1 = (sa[1][r] + sa2[1][r]*RCP2048) * 0.125f;
            float s2 = (sa[2][r] + sa2[2][r]*RCP2048) * 0.125f;
            float s3 = (sa[3][r] + sa2[3][r]*RCP2048) * 0.125f;
            float mx = fmaxf(fmaxf(s0, s1), fmaxf(s2, s3));
#pragma unroll
            for (int msk = 1; msk < 16; msk <<= 1) mx = fmaxf(mx, __shfl_xor(mx, msk));
            float mnew = fmaxf(m_i[r], mx);
            alpha[r] = __expf(m_i[r] - mnew);
            float p0 = __expf(s0 - mnew), p1 = __expf(s1 - mnew);
            float p2 = __expf(s2 - mnew), p3 = __expf(s3 - mnew);
            sa[0][r] = p0; sa[1][r] = p1; sa[2][r] = p2; sa[3][r] = p3;
            float sum = p0 + p1 + p2 + p3;
#pragma unroll
            for (int msk = 1; msk < 16; msk <<= 1) sum += __shfl_xor(sum, msk);
            l_i[r] = l_i[r] * alpha[r] + sum;
            m_i[r] = mnew;
        }
#pragma unroll
        for (int ni = 0; ni < 4; ni++)
#pragma unroll
            for (int r = 0; r < 4; r++) {
                f16 hh, ll; split_f(sa[ni][r], &hh, &ll);
                Ph[wave][quad*4 + r][ni*16 + l15] = hh;
                Pl[wave][quad*4 + r][ni*16 + l15] = ll;
            }
#pragma unroll
        for (int di = 0; di < 4; di++)
#pragma unroll
            for (int r = 0; r < 4; r++) { ao[di][r] *= alpha[r]; ao2[di][r] *= alpha[r]; }
        f16x8 pfh0 = *(const f16x8*)&Ph[wave][l15][quad * 8];
        f16x8 pfh1 = *(const f16x8*)&Ph[wave][l15][32 + quad * 8];
        f16x8 pfl0 = *(const f16x8*)&Pl[wave][l15][quad * 8];
        f16x8 pfl1 = *(const f16x8*)&Pl[wave][l15][32 + quad * 8];
#pragma unroll
        for (int di = 0; di < 4; di++) {
            const int vb = (di*16 + l15) * 64;
            f16x8 vh0 = *(const f16x8*)&Vsh[vb + ((quad       ^ sw) << 3)];
            f16x8 vh1 = *(const f16x8*)&Vsh[vb + (((quad + 4) ^ sw) << 3)];
            f16x8 vl0 = *(const f16x8*)&Vsl[vb + ((quad       ^ sw) << 3)];
            f16x8 vl1 = *(const f16x8*)&Vsl[vb + (((quad + 4) ^ sw) << 3)];
            ao[di]  = __builtin_amdgcn_mfma_f32_16x16x32_f16(pfh0, vh0, ao[di], 0, 0, 0);
            ao[di]  = __builtin_amdgcn_mfma_f32_16x16x32_f16(pfh1, vh1, ao[di], 0, 0, 0);
            ao2[di] = __builtin_amdgcn_mfma_f32_16x16x32_f16(pfh0, vl0, ao2[di], 0, 0, 0);
            ao2[di] = __builtin_amdgcn_mfma_f32_16x16x32_f16(pfh1, vl1, ao2[di], 0, 0, 0);
            ao2[di] = __builtin_amdgcn_mfma_f32_16x16x32_f16(pfl0, vh0, ao2[di], 0, 0, 0);
            ao2[di] = __builtin_amdgcn_mfma_f32_16x16x32_f16(pfl1, vh1, ao2[di], 0, 0, 0);
        }
    }
#pragma unroll
    for (int di = 0; di < 4; di++) {
#pragma unroll
        for (int r = 0; r < 4; r++) {
            size_t t = (size_t)b * 1024 + qt * 64 + wave * 16 + quad * 4 + r;
            float v = (ao[di][r] + ao2[di][r] * RCP2048) / l_i[r];
            f16 hh, ll; split_f(v, &hh, &ll);
            oh[t * 512 + h * 64 + di * 16 + l15] = hh;
            ol[t * 512 + h * 64 + di * 16 + l15] = ll;
        }
    }
}

// ---------------- gating (fp32, unchanged from round 2) ----------------
__global__ __launch_bounds__(64) void gating_k(const float* __restrict__ xn, const float* __restrict__ wg,
                                               int* __restrict__ top_i, float* __restrict__ top_g,
                                               int* __restrict__ counts) {
    int t = blockIdx.x, lane = threadIdx.x;
    const float* xr = xn + (size_t)t * 512;
    float acc[8] = {};
#pragma unroll
    for (int i = 0; i < 8; i++) {
        int d = lane + i*64;
        float xv = xr[d];
        const float* wrow = wg + (size_t)d * 8;
#pragma unroll
        for (int e = 0; e < 8; e++) acc[e] += xv * wrow[e];
    }
#pragma unroll
    for (int e = 0; e < 8; e++)
#pragma unroll
        for (int m = 32; m; m >>= 1) acc[e] += __shfl_xor(acc[e], m);
    if (lane == 0) {
        int e0 = 0; float v0 = acc[0];
        for (int e = 1; e < 8; e++) if (acc[e] > v0) { v0 = acc[e]; e0 = e; }
        int e1 = -1; float v1 = -INFINITY;
        for (int e = 0; e < 8; e++) if (e != e0 && acc[e] > v1) { v1 = acc[e]; e1 = e; }
        float g0 = 1.f / (1.f + expf(v1 - v0));
        top_i[2*t] = e0; top_i[2*t + 1] = e1;
        top_g[2*t] = g0; top_g[2*t + 1] = 1.f - g0;
        atomicAdd(&counts[e0], 1);
        atomicAdd(&counts[e1], 1);
    }
}

__global__ void zero_counts_k(int* counts) { if (threadIdx.x < 8) counts[threadIdx.x] = 0; }

__global__ void offsets_k(const int* __restrict__ counts, int* __restrict__ offs, int* __restrict__ cursor) {
    if (threadIdx.x == 0) {
        int o = 0;
        for (int e = 0; e < 8; e++) { offs[e] = o; cursor[e] = o; o += counts[e]; }
    }
}

__global__ __launch_bounds__(256) void scatter_k(const int* __restrict__ top_i, int* __restrict__ cursor,
                                                 int* __restrict__ assign_token, int* __restrict__ assign_slot) {
    int t = blockIdx.x * 256 + threadIdx.x;
#pragma unroll
    for (int k = 0; k < 2; k++) {
        int e = top_i[2*t + k];
        int pos = atomicAdd(&cursor[e], 1);
        assign_token[pos] = t;
        assign_slot[2*t + k] = pos;
    }
}

__global__ __launch_bounds__(64) void gather2_k(const f16* __restrict__ xh, const f16* __restrict__ xl,
                                                const int* __restrict__ assign_token,
                                                f16* __restrict__ oh, f16* __restrict__ ol) {
    int a = blockIdx.x, lane = threadIdx.x;
    int t = assign_token[a];
    ((uint4*)(oh + (size_t)a * 512))[lane] = ((const uint4*)(xh + (size_t)t * 512))[lane];
    ((uint4*)(ol + (size_t)a * 512))[lane] = ((const uint4*)(xl + (size_t)t * 512))[lane];
}

__global__ __launch_bounds__(64) void combine_k(float* __restrict__ x, const float* __restrict__ y,
                                                const int* __restrict__ assign_slot, const float* __restrict__ top_g) {
    int t = blockIdx.x, lane = threadIdx.x;
    int p0 = assign_slot[2*t], p1 = assign_slot[2*t + 1];
    float g0 = top_g[2*t], g1 = top_g[2*t + 1];
    float4* xr = (float4*)(x + (size_t)t * 512);
    const float4* y0 = (const float4*)(y + (size_t)p0 * 512);
    const float4* y1 = (const float4*)(y + (size_t)p1 * 512);
#pragma unroll
    for (int i = 0; i < 2; i++) {
        int idx = lane + i * 64;
        float4 a = xr[idx], c0 = y0[idx], c1 = y1[idx];
        a.x += g0*c0.x + g1*c1.x; a.y += g0*c0.y + g1*c1.y;
        a.z += g0*c0.z + g1*c1.z; a.w += g0*c0.w + g1*c1.w;
        xr[idx] = a;
    }
}

extern "C" void kernel_launch(void* const* d_in, const int* in_sizes, int n_in,
                              void* d_out, int out_size, void* d_ws, size_t ws_size,
                              hipStream_t stream) {
    const float* x_in = (const float*)d_in[0];
    const float* ln1w = (const float*)d_in[1];
    const float* ln1b = (const float*)d_in[2];
    const float* qkvw = (const float*)d_in[3];
    const float* outw = (const float*)d_in[4];
    const float* outb = (const float*)d_in[5];
    const float* ln2w = (const float*)d_in[6];
    const float* ln2b = (const float*)d_in[7];
    const float* wg   = (const float*)d_in[8];
    const float* ew1  = (const float*)d_in[9];
    const float* eb1  = (const float*)d_in[10];
    const float* ew2  = (const float*)d_in[11];
    const float* eb2  = (const float*)d_in[12];
    const float* flnw = (const float*)d_in[13];
    const float* flnb = (const float*)d_in[14];

    float* x = (float*)d_out;                         // residual [8192,512] f32

    char* ws = (char*)d_ws;
    float* xn32  = (float*)(ws + 0);                  // 16 MB
    f16*   xnh   = (f16*)(ws + 16*MB);                //  8 MB
    f16*   xnl   = (f16*)(ws + 24*MB);                //  8 MB
    f16*   qkTh  = (f16*)(ws + 32*MB);                //  1.5 MB
    f16*   qkTl  = (f16*)(ws + 34*MB);
    f16*   outTh = (f16*)(ws + 36*MB);                //  0.5 MB
    f16*   outTl = (f16*)(ws + 37*MB);
    f16*   w1Th  = (f16*)(ws + 38*MB);                // 16 MB [8][2048][512]
    f16*   w1Tl  = (f16*)(ws + 54*MB);
    f16*   w2Th  = (f16*)(ws + 70*MB);                // 16 MB [8][512][2048]
    f16*   w2Tl  = (f16*)(ws + 86*MB);
    char*  S     = ws + 102*MB;
    // attn phase
    f16*   qbh   = (f16*)(S + 0);                     // 24 MB [8192,1536]
    f16*   qbl   = (f16*)(S + 24*MB);
    f16*   vth   = (f16*)(S + 48*MB);                 //  8 MB [64][64][1024]
    f16*   vtl   = (f16*)(S + 56*MB);
    f16*   obh   = (f16*)(S + 64*MB);                 //  8 MB [8192,512]
    f16*   obl   = (f16*)(S + 72*MB);
    // moe phase (reuses S)
    f16*   xeh   = (f16*)(S + 0);                     // 16 MB [16384,512]
    f16*   xel   = (f16*)(S + 16*MB);
    f16*   hbh   = (f16*)(S + 32*MB);                 // 16 MB [16384,512] per H-slice
    f16*   hbl   = (f16*)(S + 48*MB);
    float* ybuf  = (float*)(S + 64*MB);               // 32 MB [16384,512]
    char*  SM    = ws + 198*MB;
    int*   top_i        = (int*)(SM + 0);
    float* top_g        = (float*)(SM + 65536);
    int*   assign_token = (int*)(SM + 131072);
    int*   assign_slot  = (int*)(SM + 196608);
    int*   counts       = (int*)(SM + 262144);
    int*   offs         = (int*)(SM + 262400);
    int*   cursor       = (int*)(SM + 262656);

    hipMemcpyAsync(x, x_in, (size_t)8192 * 512 * 4, hipMemcpyDeviceToDevice, stream);

    dim3 tb(32, 8);
    for (int l = 0; l < 4; l++) {
        const float* qkvw_l = qkvw + (size_t)l * 512 * 1536;
        const float* outw_l = outw + (size_t)l * 512 * 512;
        const float* ew1_l  = ew1  + (size_t)l * 8 * 512 * 2048;
        const float* ew2_l  = ew2  + (size_t)l * 8 * 2048 * 512;
        const float* eb1_l  = eb1  + (size_t)l * 8 * 2048;
        const float* eb2_l  = eb2  + (size_t)l * 8 * 512;

        // weight prep: transpose + split to fp16 hi/lo, [N,K] layout
        transpose_split_k<<<dim3(48, 16, 1), tb, 0, stream>>>(qkvw_l, qkTh, qkTl, 512, 1536, 0, 0);
        transpose_split_k<<<dim3(16, 16, 1), tb, 0, stream>>>(outw_l, outTh, outTl, 512, 512, 0, 0);
        transpose_split_k<<<dim3(64, 16, 8), tb, 0, stream>>>(ew1_l, w1Th, w1Tl, 512, 2048,
                                                              (long)512*2048, (long)512*2048);
        transpose_split_k<<<dim3(16, 64, 8), tb, 0, stream>>>(ew2_l, w2Th, w2Tl, 2048, 512,
                                                              (long)2048*512, (long)2048*512);

        // ---- attention ----
        ln_split_k<0><<<8192, 256, 0, stream>>>(x, ln1w + l*512, ln1b + l*512, nullptr, xnh, xnl);
        gemm_sp<0><<<dim3(64, 12, 1), 256, 0, stream>>>(xnh, xnl, 512, qkTh, qkTl, 512, nullptr,
                                                        qbh, qbl, 1536, 8192, 512,
                                                        nullptr, nullptr, 0, 0);
        transpose_v_k<<<dim3(32, 2, 64), tb, 0, stream>>>(qbh, vth);
        transpose_v_k<<<dim3(32, 2, 64), tb, 0, stream>>>(qbl, vtl);
        attn_sp<<<dim3(16, 64), 256, 0, stream>>>(qbh, qbl, vth, vtl, obh, obl);
        gemm_sp<1><<<dim3(64, 4, 1), 256, 0, stream>>>(obh, obl, 512, outTh, outTl, 512, outb + l*512,
                                                       x, nullptr, 512, 8192, 512,
                                                       nullptr, nullptr, 0, 0);

        // ---- MoE ----
        ln_split_k<1><<<8192, 256, 0, stream>>>(x, ln2w + l*512, ln2b + l*512, xn32, xnh, xnl);
        zero_counts_k<<<1, 64, 0, stream>>>(counts);
        gating_k<<<8192, 64, 0, stream>>>(xn32, wg + (size_t)l*512*8, top_i, top_g, counts);
        offsets_k<<<1, 1, 0, stream>>>(counts, offs, cursor);
        scatter_k<<<32, 256, 0, stream>>>(top_i, cursor, assign_token, assign_slot);
        gather2_k<<<16384, 64, 0, stream>>>(xnh, xnl, assign_token, xeh, xel);

        for (int s = 0; s < 4; s++) {
            const f16* b1h = w1Th + (size_t)s * 512 * 512;   // rows s*512.. of [2048,512]
            const f16* b1l = w1Tl + (size_t)s * 512 * 512;
            const f16* b2h = w2Th + (size_t)s * 512;         // k-cols s*512.. of [512,2048]
            const f16* b2l = w2Tl + (size_t)s * 512;
            gemm_sp<2><<<dim3(128, 4, 8), 256, 0, stream>>>(xeh, xel, 512, b1h, b1l, 512, eb1_l + s*512,
                                                            hbh, hbl, 512, 0, 512,
                                                            counts, offs, (long)2048*512, 2048);
            if (s == 0)
                gemm_sp<3><<<dim3(128, 4, 8), 256, 0, stream>>>(hbh, hbl, 512, b2h, b2l, 2048, eb2_l,
                                                                ybuf, nullptr, 512, 0, 512,
                                                                counts, offs, (long)512*2048, 512);
            else
                gemm_sp<4><<<dim3(128, 4, 8), 256, 0, stream>>>(hbh, hbl, 512, b2h, b2l, 2048, nullptr,
                                                                ybuf, nullptr, 512, 0, 512,
                                                                counts, offs, (long)512*2048, 512);
        }
        combine_k<<<8192, 64, 0, stream>>>(x, ybuf, assign_slot, top_g);
    }
    ln_k<<<8192, 256, 0, stream>>>(x, flnw, flnb, x);
}

// Round 2
// 5546.478 us; speedup vs baseline: 1.2698x; 1.1839x over previous
//
#include <hip/hip_runtime.h>
#include <cstdint>
#include <cstddef>

typedef unsigned short u16;
typedef unsigned int   u32;
typedef _Float16       f16;

typedef float f32x4 __attribute__((ext_vector_type(4)));
typedef _Float16 f16x8 __attribute__((ext_vector_type(8)));

#define MB (1024u*1024u)
#define RCP2048 (1.0f/2048.0f)

__device__ __forceinline__ float gelu_f(float u) {
    return 0.5f * u * (1.0f + erff(u * 0.70710678118654752f));
}

__device__ __forceinline__ void split_f(float v, f16* hi, f16* lo) {
    f16 h = (f16)v;
    *hi = h;
    *lo = (f16)((v - (float)h) * 2048.0f);
}

__device__ __forceinline__ void gload_lds16(const f16* g, f16* l) {
    __builtin_amdgcn_global_load_lds((const __attribute__((address_space(1))) u32*)(g),
                                     (__attribute__((address_space(3))) u32*)(l), 16, 0, 0);
}

// ---------------- transpose + split: in [R][C] f32 -> hi/lo fp16 [C][R] ----------------
__global__ void transpose_split_k(const float* __restrict__ in, f16* __restrict__ oh, f16* __restrict__ ol,
                                  int R, int C, long bsi, long bso) {
    __shared__ float tile[32][33];
    int z = blockIdx.z;
    in += (size_t)z * bsi; oh += (size_t)z * bso; ol += (size_t)z * bso;
    int c0 = blockIdx.x * 32, r0 = blockIdx.y * 32;
    int tx = threadIdx.x, ty = threadIdx.y;   // (32,8)
#pragma unroll
    for (int i = 0; i < 4; i++)
        tile[ty + i*8][tx] = in[(size_t)(r0 + ty + i*8) * C + c0 + tx];
    __syncthreads();
#pragma unroll
    for (int i = 0; i < 4; i++) {
        float v = tile[tx][ty + i*8];
        f16 h, l; split_f(v, &h, &l);
        size_t o = (size_t)(c0 + ty + i*8) * R + r0 + tx;
        oh[o] = h; ol[o] = l;
    }
}

// ---------------- f16 plane transpose (for V): src[t][1536] col-block -> vt[bh][d][n] ----------------
__global__ void transpose_v_k(const f16* __restrict__ plane, f16* __restrict__ vt) {
    __shared__ f16 tile[32][33];
    int bh = blockIdx.z; int b = bh >> 3, h = bh & 7;
    int n0 = blockIdx.x * 32, d0 = blockIdx.y * 32;
    int tx = threadIdx.x, ty = threadIdx.y;   // (32,8)
    const f16* src = plane + (size_t)b * 1024 * 1536 + 1024 + h * 64;
#pragma unroll
    for (int i = 0; i < 4; i++)
        tile[ty + i*8][tx] = src[(size_t)(n0 + ty + i*8) * 1536 + d0 + tx];
    __syncthreads();
    f16* dst = vt + (size_t)bh * 64 * 1024;
#pragma unroll
    for (int i = 0; i < 4; i++)
        dst[(size_t)(d0 + ty + i*8) * 1024 + n0 + tx] = tile[tx][ty + i*8];
}

// ---------------- LayerNorm: fp32 in -> optional fp32 out + hi/lo fp16 planes ----------------
template<int W32>
__global__ __launch_bounds__(256) void ln_split_k(const float* __restrict__ x, const float* __restrict__ w,
                                                  const float* __restrict__ b, float* __restrict__ o32,
                                                  f16* __restrict__ oh, f16* __restrict__ ol) {
    int t = blockIdx.x, tid = threadIdx.x;
    const float* xr = x + (size_t)t * 512;
    float v0 = xr[tid], v1 = xr[tid + 256];
    float s = v0 + v1, ss = v0*v0 + v1*v1;
#pragma unroll
    for (int m = 32; m; m >>= 1) { s += __shfl_xor(s, m); ss += __shfl_xor(ss, m); }
    __shared__ float red[8];
    int wv = tid >> 6;
    if ((tid & 63) == 0) { red[wv] = s; red[4 + wv] = ss; }
    __syncthreads();
    s  = red[0] + red[1] + red[2] + red[3];
    ss = red[4] + red[5] + red[6] + red[7];
    float mean = s * (1.f/512.f);
    float var  = ss * (1.f/512.f) - mean * mean;
    float rstd = rsqrtf(var + 1e-5f);
    float u0 = (v0 - mean) * rstd * w[tid]       + b[tid];
    float u1 = (v1 - mean) * rstd * w[tid + 256] + b[tid + 256];
    size_t base = (size_t)t * 512;
    if (W32) { o32[base + tid] = u0; o32[base + tid + 256] = u1; }
    f16 h0, l0, h1, l1;
    split_f(u0, &h0, &l0); split_f(u1, &h1, &l1);
    oh[base + tid] = h0; ol[base + tid] = l0;
    oh[base + tid + 256] = h1; ol[base + tid + 256] = l1;
}

// ---------------- plain fp32 LayerNorm (final) ----------------
__global__ __launch_bounds__(256) void ln_k(const float* __restrict__ x, const float* __restrict__ w,
                                            const float* __restrict__ b, float* __restrict__ out) {
    int t = blockIdx.x, tid = threadIdx.x;
    const float* xr = x + (size_t)t * 512;
    float v0 = xr[tid], v1 = xr[tid + 256];
    float s = v0 + v1, ss = v0*v0 + v1*v1;
#pragma unroll
    for (int m = 32; m; m >>= 1) { s += __shfl_xor(s, m); ss += __shfl_xor(ss, m); }
    __shared__ float red[8];
    int wv = tid >> 6;
    if ((tid & 63) == 0) { red[wv] = s; red[4 + wv] = ss; }
    __syncthreads();
    s  = red[0] + red[1] + red[2] + red[3];
    ss = red[4] + red[5] + red[6] + red[7];
    float mean = s * (1.f/512.f);
    float var  = ss * (1.f/512.f) - mean * mean;
    float rstd = rsqrtf(var + 1e-5f);
    out[(size_t)t*512 + tid]       = (v0 - mean) * rstd * w[tid]       + b[tid];
    out[(size_t)t*512 + tid + 256] = (v1 - mean) * rstd * w[tid + 256] + b[tid + 256];
}

// ---------------- split-fp16 MFMA GEMM: C = (Ah+Al/2048) @ (Bh+Bl/2048)^T ----------------
// A[M,K] hi/lo, Bt[N,K] hi/lo. 128x128 tile, BK=32, 3 MFMA products.
// EPI: 0 = split-store fp16 hi/lo; 1 = fp32 C += acc + bias; 2 = gelu(acc+bias) split-store;
//      3 = fp32 C = acc + bias; 4 = fp32 C += acc
template<int EPI>
__global__ __launch_bounds__(256) void gemm_sp(
    const f16* __restrict__ Ah, const f16* __restrict__ Al, int lda,
    const f16* __restrict__ Bh, const f16* __restrict__ Bl, int ldb,
    const float* __restrict__ bias,
    void* __restrict__ C0v, void* __restrict__ C1v, int ldc,
    int M, int K,
    const int* __restrict__ cnts, const int* __restrict__ offs,
    long bStrideZ, long biasStrideZ)
{
    int e = blockIdx.z;
    int mcnt = M;
    long aoff = 0;
    if (cnts) {
        mcnt = cnts[e];
        if ((int)(blockIdx.x * 128) >= mcnt) return;
        aoff = offs[e];
        Ah += (size_t)aoff * lda; Al += (size_t)aoff * lda;
        Bh += (size_t)e * bStrideZ; Bl += (size_t)e * bStrideZ;
        if (bias) bias += (size_t)e * biasStrideZ;
    } else if ((int)(blockIdx.x * 128) >= mcnt) return;

    f16*   C0h = (f16*)C0v   + (size_t)aoff * ldc;
    f16*   C1l = (f16*)C1v   + (size_t)aoff * ldc;
    float* Cf  = (float*)C0v + (size_t)aoff * ldc;

    const int m0 = blockIdx.x * 128, n0 = blockIdx.y * 128;
    const int tid  = threadIdx.x;
    const int wave = tid >> 6, lane = tid & 63;
    const int quad = lane >> 4, l15 = lane & 15;
    const int wr = (wave >> 1) * 64, wc = (wave & 1) * 64;

    __shared__ __align__(16) f16 Ash[4096];
    __shared__ __align__(16) f16 Asl[4096];
    __shared__ __align__(16) f16 Bsh[4096];
    __shared__ __align__(16) f16 Bsl[4096];

    f32x4 acc[4][4] = {};
    f32x4 ac2[4][4] = {};

    const int la = tid * 8;
    const int ra = tid >> 2, ca = (tid & 3) * 8;
    int r0a = m0 + ra;        if (r0a > mcnt - 1) r0a = mcnt - 1;
    int r1a = m0 + ra + 64;   if (r1a > mcnt - 1) r1a = mcnt - 1;
    const f16* ah0 = Ah + (size_t)r0a * lda + ca;
    const f16* ah1 = Ah + (size_t)r1a * lda + ca;
    const f16* al0 = Al + (size_t)r0a * lda + ca;
    const f16* al1 = Al + (size_t)r1a * lda + ca;
    const f16* bh0 = Bh + (size_t)(n0 + ra) * ldb + ca;
    const f16* bh1 = Bh + (size_t)(n0 + ra + 64) * ldb + ca;
    const f16* bl0 = Bl + (size_t)(n0 + ra) * ldb + ca;
    const f16* bl1 = Bl + (size_t)(n0 + ra + 64) * ldb + ca;

    for (int k0 = 0; k0 < K; k0 += 32) {
        __syncthreads();
        gload_lds16(ah0 + k0, &Ash[la]);
        gload_lds16(ah1 + k0, &Ash[2048 + la]);
        gload_lds16(al0 + k0, &Asl[la]);
        gload_lds16(al1 + k0, &Asl[2048 + la]);
        gload_lds16(bh0 + k0, &Bsh[la]);
        gload_lds16(bh1 + k0, &Bsh[2048 + la]);
        gload_lds16(bl0 + k0, &Bsl[la]);
        gload_lds16(bl1 + k0, &Bsl[2048 + la]);
        __syncthreads();
        f16x8 afh[4], afl[4], bfh[4], bfl[4];
#pragma unroll
        for (int mi = 0; mi < 4; mi++) {
            int ro = (wr + mi*16 + l15) * 32 + quad * 8;
            afh[mi] = *(const f16x8*)&Ash[ro];
            afl[mi] = *(const f16x8*)&Asl[ro];
        }
#pragma unroll
        for (int ni = 0; ni < 4; ni++) {
            int ro = (wc + ni*16 + l15) * 32 + quad * 8;
            bfh[ni] = *(const f16x8*)&Bsh[ro];
            bfl[ni] = *(const f16x8*)&Bsl[ro];
        }
#pragma unroll
        for (int mi = 0; mi < 4; mi++)
#pragma unroll
            for (int ni = 0; ni < 4; ni++) {
                acc[mi][ni] = __builtin_amdgcn_mfma_f32_16x16x32_f16(afh[mi], bfh[ni], acc[mi][ni], 0, 0, 0);
                ac2[mi][ni] = __builtin_amdgcn_mfma_f32_16x16x32_f16(afh[mi], bfl[ni], ac2[mi][ni], 0, 0, 0);
                ac2[mi][ni] = __builtin_amdgcn_mfma_f32_16x16x32_f16(afl[mi], bfh[ni], ac2[mi][ni], 0, 0, 0);
            }
    }

#pragma unroll
    for (int mi = 0; mi < 4; mi++) {
#pragma unroll
        for (int r = 0; r < 4; r++) {
            int row = m0 + wr + mi*16 + quad*4 + r;
            if (row >= mcnt) continue;
            size_t ro = (size_t)row * ldc;
#pragma unroll
            for (int ni = 0; ni < 4; ni++) {
                int col = n0 + wc + ni*16 + l15;
                float v = acc[mi][ni][r] + ac2[mi][ni][r] * RCP2048;
                if (EPI == 0) {
                    f16 h, l; split_f(v, &h, &l);
                    C0h[ro + col] = h; C1l[ro + col] = l;
                } else if (EPI == 1) {
                    Cf[ro + col] += v + bias[col];
                } else if (EPI == 2) {
                    float g = gelu_f(v + bias[col]);
                    f16 h, l; split_f(g, &h, &l);
                    C0h[ro + col] = h; C1l[ro + col] = l;
                } else if (EPI == 3) {
                    Cf[ro + col] = v + bias[col];
                } else {
                    Cf[ro + col] += v;
                }
            }
        }
    }
}

// ---------------- split-fp16 flash attention: grid (16 q-tiles, 64 bh), block 256 ----------------
// K/V tiles staged once per BLOCK into LDS via global_load_lds (4 waves share the same bh),
// XOR-swizzled via the global source address (linear LDS dest): slot' = slot ^ (row&7).
__global__ __launch_bounds__(256) void attn_sp(const f16* __restrict__ qh, const f16* __restrict__ ql,
                                               const f16* __restrict__ vth, const f16* __restrict__ vtl,
                                               f16* __restrict__ oh, f16* __restrict__ ol) {
    const int qt = blockIdx.x;
    const int bh = blockIdx.y;
    const int b = bh >> 3, h = bh & 7;
    const int tid = threadIdx.x;
    const int wave = tid >> 6, lane = tid & 63;
    const int quad = lane >> 4, l15 = lane & 15;

    __shared__ __align__(16) f16 Ksh[4096];   // [64 kv][64 d] hi, swizzled
    __shared__ __align__(16) f16 Ksl[4096];   // lo
    __shared__ __align__(16) f16 Vsh[4096];   // [64 d][64 kv] hi, swizzled
    __shared__ __align__(16) f16 Vsl[4096];   // lo
    __shared__ __align__(16) f16 Ph[4][16][80];
    __shared__ __align__(16) f16 Pl[4][16][80];

    const size_t tq = (size_t)b * 1024 + qt * 64 + wave * 16 + l15;
    f16x8 qh0 = *(const f16x8*)&qh[tq * 1536 + h * 64 + quad * 8];
    f16x8 qh1 = *(const f16x8*)&qh[tq * 1536 + h * 64 + 32 + quad * 8];
    f16x8 ql0 = *(const f16x8*)&ql[tq * 1536 + h * 64 + quad * 8];
    f16x8 ql1 = *(const f16x8*)&ql[tq * 1536 + h * 64 + 32 + quad * 8];

    f32x4 ao[4] = {}, ao2[4] = {};
    float m_i[4] = {-INFINITY, -INFINITY, -INFINITY, -INFINITY};
    float l_i[4] = {0.f, 0.f, 0.f, 0.f};

    const f16* kbh = qh + (size_t)b * 1024 * 1536 + 512 + h * 64;
    const f16* kbl = ql + (size_t)b * 1024 * 1536 + 512 + h * 64;
    const f16* vbh = vth + (size_t)bh * 64 * 1024;
    const f16* vbl = vtl + (size_t)bh * 64 * 1024;

    const int c0 = tid,       r0 = c0 >> 3, g0 = ((c0 & 7) ^ (r0 & 7)) * 8;
    const int c1 = tid + 256, r1 = c1 >> 3, g1 = ((c1 & 7) ^ (r1 & 7)) * 8;
    const int ko0 = r0 * 1536 + g0, ko1 = r1 * 1536 + g1;   // K: row stride 1536 f16
    const int vo0 = r0 * 1024 + g0, vo1 = r1 * 1024 + g1;   // V^T: row stride 1024 f16

    for (int kv0 = 0; kv0 < 1024; kv0 += 64) {
        __syncthreads();   // previous iteration's LDS reads complete before overwrite
        {
            const size_t kadv = (size_t)kv0 * 1536;
            gload_lds16(kbh + kadv + ko0, &Ksh[c0 * 8]);
            gload_lds16(kbh + kadv + ko1, &Ksh[c1 * 8]);
            gload_lds16(kbl + kadv + ko0, &Ksl[c0 * 8]);
            gload_lds16(kbl + kadv + ko1, &Ksl[c1 * 8]);
            gload_lds16(vbh + kv0 + vo0, &Vsh[c0 * 8]);
            gload_lds16(vbh + kv0 + vo1, &Vsh[c1 * 8]);
            gload_lds16(vbl + kv0 + vo0, &Vsl[c0 * 8]);
            gload_lds16(vbl + kv0 + vo1, &Vsl[c1 * 8]);
        }
        __syncthreads();   // drains vmcnt(0): tiles landed for all waves

        f32x4 sa[4] = {}, sa2[4] = {};
        const int sw = l15 & 7;
#pragma unroll
        for (int ni = 0; ni < 4; ni++) {
            const int kb = (ni*16 + l15) * 64;
            f16x8 kh0 = *(const f16x8*)&Ksh[kb + ((quad       ^ sw) << 3)];
            f16x8 kh1 = *(const f16x8*)&Ksh[kb + (((quad + 4) ^ sw) << 3)];
            f16x8 kl0 = *(const f16x8*)&Ksl[kb + ((quad       ^ sw) << 3)];
            f16x8 kl1 = *(const f16x8*)&Ksl[kb + (((quad + 4) ^ sw) << 3)];
            sa[ni]  = __builtin_amdgcn_mfma_f32_16x16x32_f16(qh0, kh0, sa[ni], 0, 0, 0);
            sa[ni]  = __builtin_amdgcn_mfma_f32_16x16x32_f16(qh1, kh1, sa[ni], 0, 0, 0);
            sa2[ni] = __builtin_amdgcn_mfma_f32_16x16x32_f16(qh0, kl0, sa2[ni], 0, 0, 0);
            sa2[ni] = __builtin_amdgcn_mfma_f32_16x16x32_f16(qh1, kl1, sa2[ni], 0, 0, 0);
            sa2[ni] = __builtin_amdgcn_mfma_f32_16x16x32_f16(ql0, kh0, sa2[ni], 0, 0, 0);
            sa2[ni] = __builtin_amdgcn_mfma_f32_16x16x32_f16(ql1, kh1, sa2[ni], 0, 0, 0);
        }
        float alpha[4];
#pragma unroll
        for (int r = 0; r < 4; r++) {
            float s0 = (sa[0][r] + sa2[0][r]*RCP2048) * 0.125f;
            float s1 = (sa[1][r] + sa2[1][r]*RCP2048) * 0.125f;
            float s2 = (sa[2][r] + sa2[2][r]*RCP2048) * 0.125f;
            float s3 = (sa[3][r] + sa2[3][r]*RCP2048) * 0.125f;
            float mx = fmaxf(fmaxf(s0, s1), fmaxf(s2, s3));
#pragma unroll
            for (int msk = 1; msk < 16; msk <<= 1) mx = fmaxf(mx, __shfl_xor(mx, msk));
            float mnew = fmaxf(m_i[r], mx);
            alpha[r] = __expf(m_i[r] - mnew);
            float p0 = __expf(s0 - mnew), p1 = __expf(s1 - mnew);
            float p2 = __expf(s2 - mnew), p3 = __expf(s3 - mnew);
            sa[0][r] = p0; sa[1][r] = p1; sa[2][r] = p2; sa[3][r] = p3;
            float sum = p0 + p1 + p2 + p3;
#pragma unroll
            for (int msk = 1; msk < 16; msk <<= 1) sum += __shfl_xor(sum, msk);
            l_i[r] = l_i[r] * alpha[r] + sum;
            m_i[r] = mnew;
        }
#pragma unroll
        for (int ni = 0; ni < 4; ni++)
#pragma unroll
            for (int r = 0; r < 4; r++) {
                f16 hh, ll; split_f(sa[ni][r], &hh, &ll);
                Ph[wave][quad*4 + r][ni*16 + l15] = hh;
                Pl[wave][quad*4 + r][ni*16 + l15] = ll;
            }
#pragma unroll
        for (int di = 0; di < 4; di++)
#pragma unroll
            for (int r = 0; r < 4; r++) { ao[di][r] *= alpha[r]; ao2[di][r] *= alpha[r]; }
        f16x8 pfh0 = *(const f16x8*)&Ph[wave][l15][quad * 8];
        f16x8 pfh1 = *(const f16x8*)&Ph[wave][l15][32 + quad * 8];
        f16x8 pfl0 = *(const f16x8*)&Pl[wave][l15][quad * 8];
        f16x8 pfl1 = *(const f16x8*)&Pl[wave][l15][32 + quad * 8];
#pragma unroll
        for (int di = 0; di < 4; di++) {
            const int vb = (di*16 + l15) * 64;
            f16x8 vh0 = *(const f16x8*)&Vsh[vb + ((quad       ^ sw) << 3)];
            f16x8 vh1 = *(const f16x8*)&Vsh[vb + (((quad + 4) ^ sw) << 3)];
            f16x8 vl0 = *(const f16x8*)&Vsl[vb + ((quad       ^ sw) << 3)];
            f16x8 vl1 = *(const f16x8*)&Vsl[vb + (((quad + 4) ^ sw) << 3)];
            ao[di]  = __builtin_amdgcn_mfma_f32_16x16x32_f16(pfh0, vh0, ao[di], 0, 0, 0);
            ao[di]  = __builtin_amdgcn_mfma_f32_16x16x32_f16(pfh1, vh1, ao[di], 0, 0, 0);
            ao2[di] = __builtin_amdgcn_mfma_f32_16x16x32_f16(pfh0, vl0, ao2[di], 0, 0, 0);
            ao2[di] = __builtin_amdgcn_mfma_f32_16x16x32_f16(pfh1, vl1, ao2[di], 0, 0, 0);
            ao2[di] = __builtin_amdgcn_mfma_f32_16x16x32_f16(pfl0, vh0, ao2[di], 0, 0, 0);
            ao2[di] = __builtin_amdgcn_mfma_f32_16x16x32_f16(pfl1, vh1, ao2[di], 0, 0, 0);
        }
    }
#pragma unroll
    for (int di = 0; di < 4; di++) {
#pragma unroll
        for (int r = 0; r < 4; r++) {
            size_t t = (size_t)b * 1024 + qt * 64 + wave * 16 + quad * 4 + r;
            float v = (ao[di][r] + ao2[di][r] * RCP2048) / l_i[r];
            f16 hh, ll; split_f(v, &hh, &ll);
            oh[t * 512 + h * 64 + di * 16 + l15] = hh;
            ol[t * 512 + h * 64 + di * 16 + l15] = ll;
        }
    }
}

// ---------------- gating (fp32, atomics removed — counts done by counts_k) ----------------
__global__ __launch_bounds__(64) void gating_k(const float* __restrict__ xn, const float* __restrict__ wg,
                                               int* __restrict__ top_i, float* __restrict__ top_g) {
    int t = blockIdx.x, lane = threadIdx.x;
    const float* xr = xn + (size_t)t * 512;
    float acc[8] = {};
#pragma unroll
    for (int i = 0; i < 8; i++) {
        int d = lane + i*64;
        float xv = xr[d];
        const float* wrow = wg + (size_t)d * 8;
#pragma unroll
        for (int e = 0; e < 8; e++) acc[e] += xv * wrow[e];
    }
#pragma unroll
    for (int e = 0; e < 8; e++)
#pragma unroll
        for (int m = 32; m; m >>= 1) acc[e] += __shfl_xor(acc[e], m);
    if (lane == 0) {
        int e0 = 0; float v0 = acc[0];
        for (int e = 1; e < 8; e++) if (acc[e] > v0) { v0 = acc[e]; e0 = e; }
        int e1 = -1; float v1 = -INFINITY;
        for (int e = 0; e < 8; e++) if (e != e0 && acc[e] > v1) { v1 = acc[e]; e1 = e; }
        float g0 = 1.f / (1.f + expf(v1 - v0));
        top_i[2*t] = e0; top_i[2*t + 1] = e1;
        top_g[2*t] = g0; top_g[2*t + 1] = 1.f - g0;
    }
}

__global__ void zero_counts_k(int* counts) { if (threadIdx.x < 8) counts[threadIdx.x] = 0; }

// ---------------- expert histogram: LDS-aggregated, 8 global atomics per block ----------------
__global__ __launch_bounds__(256) void counts_k(const int* __restrict__ top_i, int* __restrict__ counts) {
    __shared__ int lc[8];
    int tid = threadIdx.x;
    if (tid < 8) lc[tid] = 0;
    __syncthreads();
    int4 v = ((const int4*)top_i)[blockIdx.x * 256 + tid];   // 4 entries per thread
    atomicAdd(&lc[v.x], 1); atomicAdd(&lc[v.y], 1);
    atomicAdd(&lc[v.z], 1); atomicAdd(&lc[v.w], 1);
    __syncthreads();
    if (tid < 8) atomicAdd(&counts[tid], lc[tid]);
}

__global__ void offsets_k(const int* __restrict__ counts, int* __restrict__ offs, int* __restrict__ cursor) {
    if (threadIdx.x == 0) {
        int o = 0;
        for (int e = 0; e < 8; e++) { offs[e] = o; cursor[e] = o; o += counts[e]; }
    }
}

// ---------------- scatter: per-block LDS ranks + 8 global atomics per block ----------------
__global__ __launch_bounds__(256) void scatter_k(const int* __restrict__ top_i, int* __restrict__ cursor,
                                                 int* __restrict__ assign_token, int* __restrict__ assign_slot) {
    __shared__ int lcnt[8];
    __shared__ int base[8];
    int tid = threadIdx.x;
    int t = blockIdx.x * 256 + tid;
    if (tid < 8) lcnt[tid] = 0;
    __syncthreads();
    int e0 = top_i[2*t], e1 = top_i[2*t + 1];
    int r0 = atomicAdd(&lcnt[e0], 1);
    int r1 = atomicAdd(&lcnt[e1], 1);
    __syncthreads();
    if (tid < 8) base[tid] = atomicAdd(&cursor[tid], lcnt[tid]);
    __syncthreads();
    int p0 = base[e0] + r0, p1 = base[e1] + r1;
    assign_token[p0] = t; assign_slot[2*t]     = p0;
    assign_token[p1] = t; assign_slot[2*t + 1] = p1;
}

__global__ __launch_bounds__(64) void gather2_k(const f16* __restrict__ xh, const f16* __restrict__ xl,
                                                const int* __restrict__ assign_token,
                                                f16* __restrict__ oh, f16* __restrict__ ol) {
    int a = blockIdx.x, lane = threadIdx.x;
    int t = assign_token[a];
    ((uint4*)(oh + (size_t)a * 512))[lane] = ((const uint4*)(xh + (size_t)t * 512))[lane];
    ((uint4*)(ol + (size_t)a * 512))[lane] = ((const uint4*)(xl + (size_t)t * 512))[lane];
}

__global__ __launch_bounds__(64) void combine_k(float* __restrict__ x, const float* __restrict__ y,
                                                const int* __restrict__ assign_slot, const float* __restrict__ top_g) {
    int t = blockIdx.x, lane = threadIdx.x;
    int p0 = assign_slot[2*t], p1 = assign_slot[2*t + 1];
    float g0 = top_g[2*t], g1 = top_g[2*t + 1];
    float4* xr = (float4*)(x + (size_t)t * 512);
    const float4* y0 = (const float4*)(y + (size_t)p0 * 512);
    const float4* y1 = (const float4*)(y + (size_t)p1 * 512);
#pragma unroll
    for (int i = 0; i < 2; i++) {
        int idx = lane + i * 64;
        float4 a = xr[idx], c0 = y0[idx], c1 = y1[idx];
        a.x += g0*c0.x + g1*c1.x; a.y += g0*c0.y + g1*c1.y;
        a.z += g0*c0.z + g1*c1.z; a.w += g0*c0.w + g1*c1.w;
        xr[idx] = a;
    }
}

extern "C" void kernel_launch(void* const* d_in, const int* in_sizes, int n_in,
                              void* d_out, int out_size, void* d_ws, size_t ws_size,
                              hipStream_t stream) {
    const float* x_in = (const float*)d_in[0];
    const float* ln1w = (const float*)d_in[1];
    const float* ln1b = (const float*)d_in[2];
    const float* qkvw = (const float*)d_in[3];
    const float* outw = (const float*)d_in[4];
    const float* outb = (const float*)d_in[5];
    const float* ln2w = (const float*)d_in[6];
    const float* ln2b = (const float*)d_in[7];
    const float* wg   = (const float*)d_in[8];
    const float* ew1  = (const float*)d_in[9];
    const float* eb1  = (const float*)d_in[10];
    const float* ew2  = (const float*)d_in[11];
    const float* eb2  = (const float*)d_in[12];
    const float* flnw = (const float*)d_in[13];
    const float* flnb = (const float*)d_in[14];

    float* x = (float*)d_out;                         // residual [8192,512] f32

    char* ws = (char*)d_ws;
    float* xn32  = (float*)(ws + 0);                  // 16 MB
    f16*   xnh   = (f16*)(ws + 16*MB);                //  8 MB
    f16*   xnl   = (f16*)(ws + 24*MB);                //  8 MB
    f16*   qkTh  = (f16*)(ws + 32*MB);                //  1.5 MB
    f16*   qkTl  = (f16*)(ws + 34*MB);
    f16*   outTh = (f16*)(ws + 36*MB);                //  0.5 MB
    f16*   outTl = (f16*)(ws + 37*MB);
    f16*   w1Th  = (f16*)(ws + 38*MB);                // 16 MB [8][2048][512]
    f16*   w1Tl  = (f16*)(ws + 54*MB);
    f16*   w2Th  = (f16*)(ws + 70*MB);                // 16 MB [8][512][2048]
    f16*   w2Tl  = (f16*)(ws + 86*MB);
    char*  S     = ws + 102*MB;
    // attn phase
    f16*   qbh   = (f16*)(S + 0);                     // 24 MB [8192,1536]
    f16*   qbl   = (f16*)(S + 24*MB);
    f16*   vth   = (f16*)(S + 48*MB);                 //  8 MB [64][64][1024]
    f16*   vtl   = (f16*)(S + 56*MB);
    f16*   obh   = (f16*)(S + 64*MB);                 //  8 MB [8192,512]
    f16*   obl   = (f16*)(S + 72*MB);
    // moe phase (reuses S)
    f16*   xeh   = (f16*)(S + 0);                     // 16 MB [16384,512]
    f16*   xel   = (f16*)(S + 16*MB);
    f16*   hbh   = (f16*)(S + 32*MB);                 // 16 MB [16384,512] per H-slice
    f16*   hbl   = (f16*)(S + 48*MB);
    float* ybuf  = (float*)(S + 64*MB);               // 32 MB [16384,512]
    char*  SM    = ws + 198*MB;
    int*   top_i        = (int*)(SM + 0);
    float* top_g        = (float*)(SM + 65536);
    int*   assign_token = (int*)(SM + 131072);
    int*   assign_slot  = (int*)(SM + 196608);
    int*   counts       = (int*)(SM + 262144);
    int*   offs         = (int*)(SM + 262400);
    int*   cursor       = (int*)(SM + 262656);

    hipMemcpyAsync(x, x_in, (size_t)8192 * 512 * 4, hipMemcpyDeviceToDevice, stream);

    dim3 tb(32, 8);
    for (int l = 0; l < 4; l++) {
        const float* qkvw_l = qkvw + (size_t)l * 512 * 1536;
        const float* outw_l = outw + (size_t)l * 512 * 512;
        const float* ew1_l  = ew1  + (size_t)l * 8 * 512 * 2048;
        const float* ew2_l  = ew2  + (size_t)l * 8 * 2048 * 512;
        const float* eb1_l  = eb1  + (size_t)l * 8 * 2048;
        const float* eb2_l  = eb2  + (size_t)l * 8 * 512;

        // weight prep: transpose + split to fp16 hi/lo, [N,K] layout
        transpose_split_k<<<dim3(48, 16, 1), tb, 0, stream>>>(qkvw_l, qkTh, qkTl, 512, 1536, 0, 0);
        transpose_split_k<<<dim3(16, 16, 1), tb, 0, stream>>>(outw_l, outTh, outTl, 512, 512, 0, 0);
        transpose_split_k<<<dim3(64, 16, 8), tb, 0, stream>>>(ew1_l, w1Th, w1Tl, 512, 2048,
                                                              (long)512*2048, (long)512*2048);
        transpose_split_k<<<dim3(16, 64, 8), tb, 0, stream>>>(ew2_l, w2Th, w2Tl, 2048, 512,
                                                              (long)2048*512, (long)2048*512);

        // ---- attention ----
        ln_split_k<0><<<8192, 256, 0, stream>>>(x, ln1w + l*512, ln1b + l*512, nullptr, xnh, xnl);
        gemm_sp<0><<<dim3(64, 12, 1), 256, 0, stream>>>(xnh, xnl, 512, qkTh, qkTl, 512, nullptr,
                                                        qbh, qbl, 1536, 8192, 512,
                                                        nullptr, nullptr, 0, 0);
        transpose_v_k<<<dim3(32, 2, 64), tb, 0, stream>>>(qbh, vth);
        transpose_v_k<<<dim3(32, 2, 64), tb, 0, stream>>>(qbl, vtl);
        attn_sp<<<dim3(16, 64), 256, 0, stream>>>(qbh, qbl, vth, vtl, obh, obl);
        gemm_sp<1><<<dim3(64, 4, 1), 256, 0, stream>>>(obh, obl, 512, outTh, outTl, 512, outb + l*512,
                                                       x, nullptr, 512, 8192, 512,
                                                       nullptr, nullptr, 0, 0);

        // ---- MoE ----
        ln_split_k<1><<<8192, 256, 0, stream>>>(x, ln2w + l*512, ln2b + l*512, xn32, xnh, xnl);
        gating_k<<<8192, 64, 0, stream>>>(xn32, wg + (size_t)l*512*8, top_i, top_g);
        zero_counts_k<<<1, 64, 0, stream>>>(counts);
        counts_k<<<16, 256, 0, stream>>>(top_i, counts);
        offsets_k<<<1, 1, 0, stream>>>(counts, offs, cursor);
        scatter_k<<<32, 256, 0, stream>>>(top_i, cursor, assign_token, assign_slot);
        gather2_k<<<16384, 64, 0, stream>>>(xnh, xnl, assign_token, xeh, xel);

        for (int s = 0; s < 4; s++) {
            const f16* b1h = w1Th + (size_t)s * 512 * 512;   // rows s*512.. of [2048,512]
            const f16* b1l = w1Tl + (size_t)s * 512 * 512;
            const f16* b2h = w2Th + (size_t)s * 512;         // k-cols s*512.. of [512,2048]
            const f16* b2l = w2Tl + (size_t)s * 512;
            gemm_sp<2><<<dim3(128, 4, 8), 256, 0, stream>>>(xeh, xel, 512, b1h, b1l, 512, eb1_l + s*512,
                                                            hbh, hbl, 512, 0, 512,
                                                            counts, offs, (long)2048*512, 2048);
            if (s == 0)
                gemm_sp<3><<<dim3(128, 4, 8), 256, 0, stream>>>(hbh, hbl, 512, b2h, b2l, 2048, eb2_l,
                                                                ybuf, nullptr, 512, 0, 512,
                                                                counts, offs, (long)512*2048, 512);
            else
                gemm_sp<4><<<dim3(128, 4, 8), 256, 0, stream>>>(hbh, hbl, 512, b2h, b2l, 2048, nullptr,
                                                                ybuf, nullptr, 512, 0, 512,
                                                                counts, offs, (long)512*2048, 512);
        }
        combine_k<<<8192, 64, 0, stream>>>(x, ybuf, assign_slot, top_g);
    }
    ln_k<<<8192, 256, 0, stream>>>(x, flnw, flnb, x);
}

// Round 3
// 5135.498 us; speedup vs baseline: 1.3714x; 1.0800x over previous
//
#include <hip/hip_runtime.h>
#include <cstdint>
#include <cstddef>

typedef unsigned short u16;
typedef unsigned int   u32;
typedef _Float16       f16;

typedef float f32x4 __attribute__((ext_vector_type(4)));
typedef _Float16 f16x8 __attribute__((ext_vector_type(8)));

#define MB (1024u*1024u)
#define RCP2048 (1.0f/2048.0f)

__device__ __forceinline__ float gelu_f(float u) {
    return 0.5f * u * (1.0f + erff(u * 0.70710678118654752f));
}

__device__ __forceinline__ void split_f(float v, f16* hi, f16* lo) {
    f16 h = (f16)v;
    *hi = h;
    *lo = (f16)((v - (float)h) * 2048.0f);
}

__device__ __forceinline__ void gload_lds16(const f16* g, f16* l) {
    __builtin_amdgcn_global_load_lds((const __attribute__((address_space(1))) u32*)(g),
                                     (__attribute__((address_space(3))) u32*)(l), 16, 0, 0);
}

// ---------------- transpose + split: in [R][C] f32 -> hi/lo fp16 [C][R] ----------------
__global__ void transpose_split_k(const float* __restrict__ in, f16* __restrict__ oh, f16* __restrict__ ol,
                                  int R, int C, long bsi, long bso) {
    __shared__ float tile[32][33];
    int z = blockIdx.z;
    in += (size_t)z * bsi; oh += (size_t)z * bso; ol += (size_t)z * bso;
    int c0 = blockIdx.x * 32, r0 = blockIdx.y * 32;
    int tx = threadIdx.x, ty = threadIdx.y;   // (32,8)
#pragma unroll
    for (int i = 0; i < 4; i++)
        tile[ty + i*8][tx] = in[(size_t)(r0 + ty + i*8) * C + c0 + tx];
    __syncthreads();
#pragma unroll
    for (int i = 0; i < 4; i++) {
        float v = tile[tx][ty + i*8];
        f16 h, l; split_f(v, &h, &l);
        size_t o = (size_t)(c0 + ty + i*8) * R + r0 + tx;
        oh[o] = h; ol[o] = l;
    }
}

// ---------------- f16 plane transpose (for V): src[t][1536] col-block -> vt[bh][d][n] ----------------
__global__ void transpose_v_k(const f16* __restrict__ plane, f16* __restrict__ vt) {
    __shared__ f16 tile[32][33];
    int bh = blockIdx.z; int b = bh >> 3, h = bh & 7;
    int n0 = blockIdx.x * 32, d0 = blockIdx.y * 32;
    int tx = threadIdx.x, ty = threadIdx.y;   // (32,8)
    const f16* src = plane + (size_t)b * 1024 * 1536 + 1024 + h * 64;
#pragma unroll
    for (int i = 0; i < 4; i++)
        tile[ty + i*8][tx] = src[(size_t)(n0 + ty + i*8) * 1536 + d0 + tx];
    __syncthreads();
    f16* dst = vt + (size_t)bh * 64 * 1024;
#pragma unroll
    for (int i = 0; i < 4; i++)
        dst[(size_t)(d0 + ty + i*8) * 1024 + n0 + tx] = tile[tx][ty + i*8];
}

// ---------------- LayerNorm: fp32 in -> optional fp32 out + hi/lo fp16 planes ----------------
template<int W32>
__global__ __launch_bounds__(256) void ln_split_k(const float* __restrict__ x, const float* __restrict__ w,
                                                  const float* __restrict__ b, float* __restrict__ o32,
                                                  f16* __restrict__ oh, f16* __restrict__ ol) {
    int t = blockIdx.x, tid = threadIdx.x;
    const float* xr = x + (size_t)t * 512;
    float v0 = xr[tid], v1 = xr[tid + 256];
    float s = v0 + v1, ss = v0*v0 + v1*v1;
#pragma unroll
    for (int m = 32; m; m >>= 1) { s += __shfl_xor(s, m); ss += __shfl_xor(ss, m); }
    __shared__ float red[8];
    int wv = tid >> 6;
    if ((tid & 63) == 0) { red[wv] = s; red[4 + wv] = ss; }
    __syncthreads();
    s  = red[0] + red[1] + red[2] + red[3];
    ss = red[4] + red[5] + red[6] + red[7];
    float mean = s * (1.f/512.f);
    float var  = ss * (1.f/512.f) - mean * mean;
    float rstd = rsqrtf(var + 1e-5f);
    float u0 = (v0 - mean) * rstd * w[tid]       + b[tid];
    float u1 = (v1 - mean) * rstd * w[tid + 256] + b[tid + 256];
    size_t base = (size_t)t * 512;
    if (W32) { o32[base + tid] = u0; o32[base + tid + 256] = u1; }
    f16 h0, l0, h1, l1;
    split_f(u0, &h0, &l0); split_f(u1, &h1, &l1);
    oh[base + tid] = h0; ol[base + tid] = l0;
    oh[base + tid + 256] = h1; ol[base + tid + 256] = l1;
}

// ---------------- plain fp32 LayerNorm (final) ----------------
__global__ __launch_bounds__(256) void ln_k(const float* __restrict__ x, const float* __restrict__ w,
                                            const float* __restrict__ b, float* __restrict__ out) {
    int t = blockIdx.x, tid = threadIdx.x;
    const float* xr = x + (size_t)t * 512;
    float v0 = xr[tid], v1 = xr[tid + 256];
    float s = v0 + v1, ss = v0*v0 + v1*v1;
#pragma unroll
    for (int m = 32; m; m >>= 1) { s += __shfl_xor(s, m); ss += __shfl_xor(ss, m); }
    __shared__ float red[8];
    int wv = tid >> 6;
    if ((tid & 63) == 0) { red[wv] = s; red[4 + wv] = ss; }
    __syncthreads();
    s  = red[0] + red[1] + red[2] + red[3];
    ss = red[4] + red[5] + red[6] + red[7];
    float mean = s * (1.f/512.f);
    float var  = ss * (1.f/512.f) - mean * mean;
    float rstd = rsqrtf(var + 1e-5f);
    out[(size_t)t*512 + tid]       = (v0 - mean) * rstd * w[tid]       + b[tid];
    out[(size_t)t*512 + tid + 256] = (v1 - mean) * rstd * w[tid + 256] + b[tid + 256];
}

// ---------------- split-fp16 MFMA GEMM: C = (Ah+Al/2048) @ (Bh+Bl/2048)^T ----------------
// A[M,K] hi/lo, Bt[N,K] hi/lo. 128x128 tile, BK=32, 3 MFMA products.
// Double-buffered LDS: stage tile k+1 while computing tile k; ONE barrier per K-step
// (its implicit vmcnt(0) drains the stage issued a full compute-phase earlier).
// EPI: 0 = split-store fp16 hi/lo; 1 = fp32 C += acc + bias; 2 = gelu(acc+bias) split-store;
//      3 = fp32 C = acc + bias; 4 = fp32 C += acc
template<int EPI>
__global__ __launch_bounds__(256) void gemm_sp(
    const f16* __restrict__ Ah, const f16* __restrict__ Al, int lda,
    const f16* __restrict__ Bh, const f16* __restrict__ Bl, int ldb,
    const float* __restrict__ bias,
    void* __restrict__ C0v, void* __restrict__ C1v, int ldc,
    int M, int K,
    const int* __restrict__ cnts, const int* __restrict__ offs,
    long bStrideZ, long biasStrideZ)
{
    int e = blockIdx.z;
    int mcnt = M;
    long aoff = 0;
    if (cnts) {
        mcnt = cnts[e];
        if ((int)(blockIdx.x * 128) >= mcnt) return;
        aoff = offs[e];
        Ah += (size_t)aoff * lda; Al += (size_t)aoff * lda;
        Bh += (size_t)e * bStrideZ; Bl += (size_t)e * bStrideZ;
        if (bias) bias += (size_t)e * biasStrideZ;
    } else if ((int)(blockIdx.x * 128) >= mcnt) return;

    f16*   C0h = (f16*)C0v   + (size_t)aoff * ldc;
    f16*   C1l = (f16*)C1v   + (size_t)aoff * ldc;
    float* Cf  = (float*)C0v + (size_t)aoff * ldc;

    const int m0 = blockIdx.x * 128, n0 = blockIdx.y * 128;
    const int tid  = threadIdx.x;
    const int wave = tid >> 6, lane = tid & 63;
    const int quad = lane >> 4, l15 = lane & 15;
    const int wr = (wave >> 1) * 64, wc = (wave & 1) * 64;

    __shared__ __align__(16) f16 Ash[2][4096];
    __shared__ __align__(16) f16 Asl[2][4096];
    __shared__ __align__(16) f16 Bsh[2][4096];
    __shared__ __align__(16) f16 Bsl[2][4096];

    f32x4 acc[4][4] = {};
    f32x4 ac2[4][4] = {};

    const int la = tid * 8;
    const int ra = tid >> 2, ca = (tid & 3) * 8;
    int r0a = m0 + ra;        if (r0a > mcnt - 1) r0a = mcnt - 1;
    int r1a = m0 + ra + 64;   if (r1a > mcnt - 1) r1a = mcnt - 1;
    const f16* ah0 = Ah + (size_t)r0a * lda + ca;
    const f16* ah1 = Ah + (size_t)r1a * lda + ca;
    const f16* al0 = Al + (size_t)r0a * lda + ca;
    const f16* al1 = Al + (size_t)r1a * lda + ca;
    const f16* bh0 = Bh + (size_t)(n0 + ra) * ldb + ca;
    const f16* bh1 = Bh + (size_t)(n0 + ra + 64) * ldb + ca;
    const f16* bl0 = Bl + (size_t)(n0 + ra) * ldb + ca;
    const f16* bl1 = Bl + (size_t)(n0 + ra + 64) * ldb + ca;

    auto stage = [&](int k0, int buf) {
        gload_lds16(ah0 + k0, &Ash[buf][la]);
        gload_lds16(ah1 + k0, &Ash[buf][2048 + la]);
        gload_lds16(al0 + k0, &Asl[buf][la]);
        gload_lds16(al1 + k0, &Asl[buf][2048 + la]);
        gload_lds16(bh0 + k0, &Bsh[buf][la]);
        gload_lds16(bh1 + k0, &Bsh[buf][2048 + la]);
        gload_lds16(bl0 + k0, &Bsl[buf][la]);
        gload_lds16(bl1 + k0, &Bsl[buf][2048 + la]);
    };

    stage(0, 0);
    __syncthreads();           // drains vmcnt(0): tile 0 landed

    int cur = 0;
    for (int k0 = 0; k0 < K; k0 += 32) {
        if (k0 + 32 < K) stage(k0 + 32, cur ^ 1);   // prefetch next tile (overlaps compute below)
        f16x8 afh[4], afl[4], bfh[4], bfl[4];
#pragma unroll
        for (int mi = 0; mi < 4; mi++) {
            int ro = (wr + mi*16 + l15) * 32 + quad * 8;
            afh[mi] = *(const f16x8*)&Ash[cur][ro];
            afl[mi] = *(const f16x8*)&Asl[cur][ro];
        }
#pragma unroll
        for (int ni = 0; ni < 4; ni++) {
            int ro = (wc + ni*16 + l15) * 32 + quad * 8;
            bfh[ni] = *(const f16x8*)&Bsh[cur][ro];
            bfl[ni] = *(const f16x8*)&Bsl[cur][ro];
        }
#pragma unroll
        for (int mi = 0; mi < 4; mi++)
#pragma unroll
            for (int ni = 0; ni < 4; ni++) {
                acc[mi][ni] = __builtin_amdgcn_mfma_f32_16x16x32_f16(afh[mi], bfh[ni], acc[mi][ni], 0, 0, 0);
                ac2[mi][ni] = __builtin_amdgcn_mfma_f32_16x16x32_f16(afh[mi], bfl[ni], ac2[mi][ni], 0, 0, 0);
                ac2[mi][ni] = __builtin_amdgcn_mfma_f32_16x16x32_f16(afl[mi], bfh[ni], ac2[mi][ni], 0, 0, 0);
            }
        __syncthreads();       // drains vmcnt(0) (next tile) + protects buf reuse
        cur ^= 1;
    }

#pragma unroll
    for (int mi = 0; mi < 4; mi++) {
#pragma unroll
        for (int r = 0; r < 4; r++) {
            int row = m0 + wr + mi*16 + quad*4 + r;
            if (row >= mcnt) continue;
            size_t ro = (size_t)row * ldc;
#pragma unroll
            for (int ni = 0; ni < 4; ni++) {
                int col = n0 + wc + ni*16 + l15;
                float v = acc[mi][ni][r] + ac2[mi][ni][r] * RCP2048;
                if (EPI == 0) {
                    f16 h, l; split_f(v, &h, &l);
                    C0h[ro + col] = h; C1l[ro + col] = l;
                } else if (EPI == 1) {
                    Cf[ro + col] += v + bias[col];
                } else if (EPI == 2) {
                    float g = gelu_f(v + bias[col]);
                    f16 h, l; split_f(g, &h, &l);
                    C0h[ro + col] = h; C1l[ro + col] = l;
                } else if (EPI == 3) {
                    Cf[ro + col] = v + bias[col];
                } else {
                    Cf[ro + col] += v;
                }
            }
        }
    }
}

// ---------------- split-fp16 flash attention: grid (16 q-tiles, 64 bh), block 256 ----------------
// K/V tiles staged once per BLOCK into LDS via global_load_lds (4 waves share the same bh),
// XOR-swizzled via the global source address (linear LDS dest): slot' = slot ^ (row&7).
__global__ __launch_bounds__(256) void attn_sp(const f16* __restrict__ qh, const f16* __restrict__ ql,
                                               const f16* __restrict__ vth, const f16* __restrict__ vtl,
                                               f16* __restrict__ oh, f16* __restrict__ ol) {
    const int qt = blockIdx.x;
    const int bh = blockIdx.y;
    const int b = bh >> 3, h = bh & 7;
    const int tid = threadIdx.x;
    const int wave = tid >> 6, lane = tid & 63;
    const int quad = lane >> 4, l15 = lane & 15;

    __shared__ __align__(16) f16 Ksh[4096];   // [64 kv][64 d] hi, swizzled
    __shared__ __align__(16) f16 Ksl[4096];   // lo
    __shared__ __align__(16) f16 Vsh[4096];   // [64 d][64 kv] hi, swizzled
    __shared__ __align__(16) f16 Vsl[4096];   // lo
    __shared__ __align__(16) f16 Ph[4][16][80];
    __shared__ __align__(16) f16 Pl[4][16][80];

    const size_t tq = (size_t)b * 1024 + qt * 64 + wave * 16 + l15;
    f16x8 qh0 = *(const f16x8*)&qh[tq * 1536 + h * 64 + quad * 8];
    f16x8 qh1 = *(const f16x8*)&qh[tq * 1536 + h * 64 + 32 + quad * 8];
    f16x8 ql0 = *(const f16x8*)&ql[tq * 1536 + h * 64 + quad * 8];
    f16x8 ql1 = *(const f16x8*)&ql[tq * 1536 + h * 64 + 32 + quad * 8];

    f32x4 ao[4] = {}, ao2[4] = {};
    float m_i[4] = {-INFINITY, -INFINITY, -INFINITY, -INFINITY};
    float l_i[4] = {0.f, 0.f, 0.f, 0.f};

    const f16* kbh = qh + (size_t)b * 1024 * 1536 + 512 + h * 64;
    const f16* kbl = ql + (size_t)b * 1024 * 1536 + 512 + h * 64;
    const f16* vbh = vth + (size_t)bh * 64 * 1024;
    const f16* vbl = vtl + (size_t)bh * 64 * 1024;

    const int c0 = tid,       r0 = c0 >> 3, g0 = ((c0 & 7) ^ (r0 & 7)) * 8;
    const int c1 = tid + 256, r1 = c1 >> 3, g1 = ((c1 & 7) ^ (r1 & 7)) * 8;
    const int ko0 = r0 * 1536 + g0, ko1 = r1 * 1536 + g1;   // K: row stride 1536 f16
    const int vo0 = r0 * 1024 + g0, vo1 = r1 * 1024 + g1;   // V^T: row stride 1024 f16

    for (int kv0 = 0; kv0 < 1024; kv0 += 64) {
        __syncthreads();   // previous iteration's LDS reads complete before overwrite
        {
            const size_t kadv = (size_t)kv0 * 1536;
            gload_lds16(kbh + kadv + ko0, &Ksh[c0 * 8]);
            gload_lds16(kbh + kadv + ko1, &Ksh[c1 * 8]);
            gload_lds16(kbl + kadv + ko0, &Ksl[c0 * 8]);
            gload_lds16(kbl + kadv + ko1, &Ksl[c1 * 8]);
            gload_lds16(vbh + kv0 + vo0, &Vsh[c0 * 8]);
            gload_lds16(vbh + kv0 + vo1, &Vsh[c1 * 8]);
            gload_lds16(vbl + kv0 + vo0, &Vsl[c0 * 8]);
            gload_lds16(vbl + kv0 + vo1, &Vsl[c1 * 8]);
        }
        __syncthreads();   // drains vmcnt(0): tiles landed for all waves

        f32x4 sa[4] = {}, sa2[4] = {};
        const int sw = l15 & 7;
#pragma unroll
        for (int ni = 0; ni < 4; ni++) {
            const int kb = (ni*16 + l15) * 64;
            f16x8 kh0 = *(const f16x8*)&Ksh[kb + ((quad       ^ sw) << 3)];
            f16x8 kh1 = *(const f16x8*)&Ksh[kb + (((quad + 4) ^ sw) << 3)];
            f16x8 kl0 = *(const f16x8*)&Ksl[kb + ((quad       ^ sw) << 3)];
            f16x8 kl1 = *(const f16x8*)&Ksl[kb + (((quad + 4) ^ sw) << 3)];
            sa[ni]  = __builtin_amdgcn_mfma_f32_16x16x32_f16(qh0, kh0, sa[ni], 0, 0, 0);
            sa[ni]  = __builtin_amdgcn_mfma_f32_16x16x32_f16(qh1, kh1, sa[ni], 0, 0, 0);
            sa2[ni] = __builtin_amdgcn_mfma_f32_16x16x32_f16(qh0, kl0, sa2[ni], 0, 0, 0);
            sa2[ni] = __builtin_amdgcn_mfma_f32_16x16x32_f16(qh1, kl1, sa2[ni], 0, 0, 0);
            sa2[ni] = __builtin_amdgcn_mfma_f32_16x16x32_f16(ql0, kh0, sa2[ni], 0, 0, 0);
            sa2[ni] = __builtin_amdgcn_mfma_f32_16x16x32_f16(ql1, kh1, sa2[ni], 0, 0, 0);
        }
        float alpha[4];
#pragma unroll
        for (int r = 0; r < 4; r++) {
            float s0 = (sa[0][r] + sa2[0][r]*RCP2048) * 0.125f;
            float s1 = (sa[1][r] + sa2[1][r]*RCP2048) * 0.125f;
            float s2 = (sa[2][r] + sa2[2][r]*RCP2048) * 0.125f;
            float s3 = (sa[3][r] + sa2[3][r]*RCP2048) * 0.125f;
            float mx = fmaxf(fmaxf(s0, s1), fmaxf(s2, s3));
#pragma unroll
            for (int msk = 1; msk < 16; msk <<= 1) mx = fmaxf(mx, __shfl_xor(mx, msk));
            float mnew = fmaxf(m_i[r], mx);
            alpha[r] = __expf(m_i[r] - mnew);
            float p0 = __expf(s0 - mnew), p1 = __expf(s1 - mnew);
            float p2 = __expf(s2 - mnew), p3 = __expf(s3 - mnew);
            sa[0][r] = p0; sa[1][r] = p1; sa[2][r] = p2; sa[3][r] = p3;
            float sum = p0 + p1 + p2 + p3;
#pragma unroll
            for (int msk = 1; msk < 16; msk <<= 1) sum += __shfl_xor(sum, msk);
            l_i[r] = l_i[r] * alpha[r] + sum;
            m_i[r] = mnew;
        }
#pragma unroll
        for (int ni = 0; ni < 4; ni++)
#pragma unroll
            for (int r = 0; r < 4; r++) {
                f16 hh, ll; split_f(sa[ni][r], &hh, &ll);
                Ph[wave][quad*4 + r][ni*16 + l15] = hh;
                Pl[wave][quad*4 + r][ni*16 + l15] = ll;
            }
#pragma unroll
        for (int di = 0; di < 4; di++)
#pragma unroll
            for (int r = 0; r < 4; r++) { ao[di][r] *= alpha[r]; ao2[di][r] *= alpha[r]; }
        f16x8 pfh0 = *(const f16x8*)&Ph[wave][l15][quad * 8];
        f16x8 pfh1 = *(const f16x8*)&Ph[wave][l15][32 + quad * 8];
        f16x8 pfl0 = *(const f16x8*)&Pl[wave][l15][quad * 8];
        f16x8 pfl1 = *(const f16x8*)&Pl[wave][l15][32 + quad * 8];
#pragma unroll
        for (int di = 0; di < 4; di++) {
            const int vb = (di*16 + l15) * 64;
            f16x8 vh0 = *(const f16x8*)&Vsh[vb + ((quad       ^ sw) << 3)];
            f16x8 vh1 = *(const f16x8*)&Vsh[vb + (((quad + 4) ^ sw) << 3)];
            f16x8 vl0 = *(const f16x8*)&Vsl[vb + ((quad       ^ sw) << 3)];
            f16x8 vl1 = *(const f16x8*)&Vsl[vb + (((quad + 4) ^ sw) << 3)];
            ao[di]  = __builtin_amdgcn_mfma_f32_16x16x32_f16(pfh0, vh0, ao[di], 0, 0, 0);
            ao[di]  = __builtin_amdgcn_mfma_f32_16x16x32_f16(pfh1, vh1, ao[di], 0, 0, 0);
            ao2[di] = __builtin_amdgcn_mfma_f32_16x16x32_f16(pfh0, vl0, ao2[di], 0, 0, 0);
            ao2[di] = __builtin_amdgcn_mfma_f32_16x16x32_f16(pfh1, vl1, ao2[di], 0, 0, 0);
            ao2[di] = __builtin_amdgcn_mfma_f32_16x16x32_f16(pfl0, vh0, ao2[di], 0, 0, 0);
            ao2[di] = __builtin_amdgcn_mfma_f32_16x16x32_f16(pfl1, vh1, ao2[di], 0, 0, 0);
        }
    }
#pragma unroll
    for (int di = 0; di < 4; di++) {
#pragma unroll
        for (int r = 0; r < 4; r++) {
            size_t t = (size_t)b * 1024 + qt * 64 + wave * 16 + quad * 4 + r;
            float v = (ao[di][r] + ao2[di][r] * RCP2048) / l_i[r];
            f16 hh, ll; split_f(v, &hh, &ll);
            oh[t * 512 + h * 64 + di * 16 + l15] = hh;
            ol[t * 512 + h * 64 + di * 16 + l15] = ll;
        }
    }
}

// ---------------- gating (fp32, atomics removed — counts done by counts_k) ----------------
__global__ __launch_bounds__(64) void gating_k(const float* __restrict__ xn, const float* __restrict__ wg,
                                               int* __restrict__ top_i, float* __restrict__ top_g) {
    int t = blockIdx.x, lane = threadIdx.x;
    const float* xr = xn + (size_t)t * 512;
    float acc[8] = {};
#pragma unroll
    for (int i = 0; i < 8; i++) {
        int d = lane + i*64;
        float xv = xr[d];
        const float* wrow = wg + (size_t)d * 8;
#pragma unroll
        for (int e = 0; e < 8; e++) acc[e] += xv * wrow[e];
    }
#pragma unroll
    for (int e = 0; e < 8; e++)
#pragma unroll
        for (int m = 32; m; m >>= 1) acc[e] += __shfl_xor(acc[e], m);
    if (lane == 0) {
        int e0 = 0; float v0 = acc[0];
        for (int e = 1; e < 8; e++) if (acc[e] > v0) { v0 = acc[e]; e0 = e; }
        int e1 = -1; float v1 = -INFINITY;
        for (int e = 0; e < 8; e++) if (e != e0 && acc[e] > v1) { v1 = acc[e]; e1 = e; }
        float g0 = 1.f / (1.f + expf(v1 - v0));
        top_i[2*t] = e0; top_i[2*t + 1] = e1;
        top_g[2*t] = g0; top_g[2*t + 1] = 1.f - g0;
    }
}

__global__ void zero_counts_k(int* counts) { if (threadIdx.x < 8) counts[threadIdx.x] = 0; }

// ---------------- expert histogram: LDS-aggregated, 8 global atomics per block ----------------
__global__ __launch_bounds__(256) void counts_k(const int* __restrict__ top_i, int* __restrict__ counts) {
    __shared__ int lc[8];
    int tid = threadIdx.x;
    if (tid < 8) lc[tid] = 0;
    __syncthreads();
    int4 v = ((const int4*)top_i)[blockIdx.x * 256 + tid];   // 4 entries per thread
    atomicAdd(&lc[v.x], 1); atomicAdd(&lc[v.y], 1);
    atomicAdd(&lc[v.z], 1); atomicAdd(&lc[v.w], 1);
    __syncthreads();
    if (tid < 8) atomicAdd(&counts[tid], lc[tid]);
}

__global__ void offsets_k(const int* __restrict__ counts, int* __restrict__ offs, int* __restrict__ cursor) {
    if (threadIdx.x == 0) {
        int o = 0;
        for (int e = 0; e < 8; e++) { offs[e] = o; cursor[e] = o; o += counts[e]; }
    }
}

// ---------------- scatter: per-block LDS ranks + 8 global atomics per block ----------------
__global__ __launch_bounds__(256) void scatter_k(const int* __restrict__ top_i, int* __restrict__ cursor,
                                                 int* __restrict__ assign_token, int* __restrict__ assign_slot) {
    __shared__ int lcnt[8];
    __shared__ int base[8];
    int tid = threadIdx.x;
    int t = blockIdx.x * 256 + tid;
    if (tid < 8) lcnt[tid] = 0;
    __syncthreads();
    int e0 = top_i[2*t], e1 = top_i[2*t + 1];
    int r0 = atomicAdd(&lcnt[e0], 1);
    int r1 = atomicAdd(&lcnt[e1], 1);
    __syncthreads();
    if (tid < 8) base[tid] = atomicAdd(&cursor[tid], lcnt[tid]);
    __syncthreads();
    int p0 = base[e0] + r0, p1 = base[e1] + r1;
    assign_token[p0] = t; assign_slot[2*t]     = p0;
    assign_token[p1] = t; assign_slot[2*t + 1] = p1;
}

__global__ __launch_bounds__(64) void gather2_k(const f16* __restrict__ xh, const f16* __restrict__ xl,
                                                const int* __restrict__ assign_token,
                                                f16* __restrict__ oh, f16* __restrict__ ol) {
    int a = blockIdx.x, lane = threadIdx.x;
    int t = assign_token[a];
    ((uint4*)(oh + (size_t)a * 512))[lane] = ((const uint4*)(xh + (size_t)t * 512))[lane];
    ((uint4*)(ol + (size_t)a * 512))[lane] = ((const uint4*)(xl + (size_t)t * 512))[lane];
}

__global__ __launch_bounds__(64) void combine_k(float* __restrict__ x, const float* __restrict__ y,
                                                const int* __restrict__ assign_slot, const float* __restrict__ top_g) {
    int t = blockIdx.x, lane = threadIdx.x;
    int p0 = assign_slot[2*t], p1 = assign_slot[2*t + 1];
    float g0 = top_g[2*t], g1 = top_g[2*t + 1];
    float4* xr = (float4*)(x + (size_t)t * 512);
    const float4* y0 = (const float4*)(y + (size_t)p0 * 512);
    const float4* y1 = (const float4*)(y + (size_t)p1 * 512);
#pragma unroll
    for (int i = 0; i < 2; i++) {
        int idx = lane + i * 64;
        float4 a = xr[idx], c0 = y0[idx], c1 = y1[idx];
        a.x += g0*c0.x + g1*c1.x; a.y += g0*c0.y + g1*c1.y;
        a.z += g0*c0.z + g1*c1.z; a.w += g0*c0.w + g1*c1.w;
        xr[idx] = a;
    }
}

extern "C" void kernel_launch(void* const* d_in, const int* in_sizes, int n_in,
                              void* d_out, int out_size, void* d_ws, size_t ws_size,
                              hipStream_t stream) {
    const float* x_in = (const float*)d_in[0];
    const float* ln1w = (const float*)d_in[1];
    const float* ln1b = (const float*)d_in[2];
    const float* qkvw = (const float*)d_in[3];
    const float* outw = (const float*)d_in[4];
    const float* outb = (const float*)d_in[5];
    const float* ln2w = (const float*)d_in[6];
    const float* ln2b = (const float*)d_in[7];
    const float* wg   = (const float*)d_in[8];
    const float* ew1  = (const float*)d_in[9];
    const float* eb1  = (const float*)d_in[10];
    const float* ew2  = (const float*)d_in[11];
    const float* eb2  = (const float*)d_in[12];
    const float* flnw = (const float*)d_in[13];
    const float* flnb = (const float*)d_in[14];

    float* x = (float*)d_out;                         // residual [8192,512] f32

    char* ws = (char*)d_ws;
    float* xn32  = (float*)(ws + 0);                  // 16 MB
    f16*   xnh   = (f16*)(ws + 16*MB);                //  8 MB
    f16*   xnl   = (f16*)(ws + 24*MB);                //  8 MB
    f16*   qkTh  = (f16*)(ws + 32*MB);                //  1.5 MB
    f16*   qkTl  = (f16*)(ws + 34*MB);
    f16*   outTh = (f16*)(ws + 36*MB);                //  0.5 MB
    f16*   outTl = (f16*)(ws + 37*MB);
    f16*   w1Th  = (f16*)(ws + 38*MB);                // 16 MB [8][2048][512]
    f16*   w1Tl  = (f16*)(ws + 54*MB);
    f16*   w2Th  = (f16*)(ws + 70*MB);                // 16 MB [8][512][2048]
    f16*   w2Tl  = (f16*)(ws + 86*MB);
    char*  S     = ws + 102*MB;
    // attn phase
    f16*   qbh   = (f16*)(S + 0);                     // 24 MB [8192,1536]
    f16*   qbl   = (f16*)(S + 24*MB);
    f16*   vth   = (f16*)(S + 48*MB);                 //  8 MB [64][64][1024]
    f16*   vtl   = (f16*)(S + 56*MB);
    f16*   obh   = (f16*)(S + 64*MB);                 //  8 MB [8192,512]
    f16*   obl   = (f16*)(S + 72*MB);
    // moe phase (reuses S)
    f16*   xeh   = (f16*)(S + 0);                     // 16 MB [16384,512]
    f16*   xel   = (f16*)(S + 16*MB);
    f16*   hbh   = (f16*)(S + 32*MB);                 // 16 MB [16384,512] per H-slice
    f16*   hbl   = (f16*)(S + 48*MB);
    float* ybuf  = (float*)(S + 64*MB);               // 32 MB [16384,512]
    char*  SM    = ws + 198*MB;
    int*   top_i        = (int*)(SM + 0);
    float* top_g        = (float*)(SM + 65536);
    int*   assign_token = (int*)(SM + 131072);
    int*   assign_slot  = (int*)(SM + 196608);
    int*   counts       = (int*)(SM + 262144);
    int*   offs         = (int*)(SM + 262400);
    int*   cursor       = (int*)(SM + 262656);

    hipMemcpyAsync(x, x_in, (size_t)8192 * 512 * 4, hipMemcpyDeviceToDevice, stream);

    dim3 tb(32, 8);
    for (int l = 0; l < 4; l++) {
        const float* qkvw_l = qkvw + (size_t)l * 512 * 1536;
        const float* outw_l = outw + (size_t)l * 512 * 512;
        const float* ew1_l  = ew1  + (size_t)l * 8 * 512 * 2048;
        const float* ew2_l  = ew2  + (size_t)l * 8 * 2048 * 512;
        const float* eb1_l  = eb1  + (size_t)l * 8 * 2048;
        const float* eb2_l  = eb2  + (size_t)l * 8 * 512;

        // weight prep: transpose + split to fp16 hi/lo, [N,K] layout
        transpose_split_k<<<dim3(48, 16, 1), tb, 0, stream>>>(qkvw_l, qkTh, qkTl, 512, 1536, 0, 0);
        transpose_split_k<<<dim3(16, 16, 1), tb, 0, stream>>>(outw_l, outTh, outTl, 512, 512, 0, 0);
        transpose_split_k<<<dim3(64, 16, 8), tb, 0, stream>>>(ew1_l, w1Th, w1Tl, 512, 2048,
                                                              (long)512*2048, (long)512*2048);
        transpose_split_k<<<dim3(16, 64, 8), tb, 0, stream>>>(ew2_l, w2Th, w2Tl, 2048, 512,
                                                              (long)2048*512, (long)2048*512);

        // ---- attention ----
        ln_split_k<0><<<8192, 256, 0, stream>>>(x, ln1w + l*512, ln1b + l*512, nullptr, xnh, xnl);
        gemm_sp<0><<<dim3(64, 12, 1), 256, 0, stream>>>(xnh, xnl, 512, qkTh, qkTl, 512, nullptr,
                                                        qbh, qbl, 1536, 8192, 512,
                                                        nullptr, nullptr, 0, 0);
        transpose_v_k<<<dim3(32, 2, 64), tb, 0, stream>>>(qbh, vth);
        transpose_v_k<<<dim3(32, 2, 64), tb, 0, stream>>>(qbl, vtl);
        attn_sp<<<dim3(16, 64), 256, 0, stream>>>(qbh, qbl, vth, vtl, obh, obl);
        gemm_sp<1><<<dim3(64, 4, 1), 256, 0, stream>>>(obh, obl, 512, outTh, outTl, 512, outb + l*512,
                                                       x, nullptr, 512, 8192, 512,
                                                       nullptr, nullptr, 0, 0);

        // ---- MoE ----
        ln_split_k<1><<<8192, 256, 0, stream>>>(x, ln2w + l*512, ln2b + l*512, xn32, xnh, xnl);
        gating_k<<<8192, 64, 0, stream>>>(xn32, wg + (size_t)l*512*8, top_i, top_g);
        zero_counts_k<<<1, 64, 0, stream>>>(counts);
        counts_k<<<16, 256, 0, stream>>>(top_i, counts);
        offsets_k<<<1, 1, 0, stream>>>(counts, offs, cursor);
        scatter_k<<<32, 256, 0, stream>>>(top_i, cursor, assign_token, assign_slot);
        gather2_k<<<16384, 64, 0, stream>>>(xnh, xnl, assign_token, xeh, xel);

        for (int s = 0; s < 4; s++) {
            const f16* b1h = w1Th + (size_t)s * 512 * 512;   // rows s*512.. of [2048,512]
            const f16* b1l = w1Tl + (size_t)s * 512 * 512;
            const f16* b2h = w2Th + (size_t)s * 512;         // k-cols s*512.. of [512,2048]
            const f16* b2l = w2Tl + (size_t)s * 512;
            gemm_sp<2><<<dim3(64, 4, 8), 256, 0, stream>>>(xeh, xel, 512, b1h, b1l, 512, eb1_l + s*512,
                                                           hbh, hbl, 512, 0, 512,
                                                           counts, offs, (long)2048*512, 2048);
            if (s == 0)
                gemm_sp<3><<<dim3(64, 4, 8), 256, 0, stream>>>(hbh, hbl, 512, b2h, b2l, 2048, eb2_l,
                                                               ybuf, nullptr, 512, 0, 512,
                                                               counts, offs, (long)512*2048, 512);
            else
                gemm_sp<4><<<dim3(64, 4, 8), 256, 0, stream>>>(hbh, hbl, 512, b2h, b2l, 2048, nullptr,
                                                               ybuf, nullptr, 512, 0, 512,
                                                               counts, offs, (long)512*2048, 512);
        }
        combine_k<<<8192, 64, 0, stream>>>(x, ybuf, assign_slot, top_g);
    }
    ln_k<<<8192, 256, 0, stream>>>(x, flnw, flnb, x);
}

// Round 4
// 4932.013 us; speedup vs baseline: 1.4280x; 1.0413x over previous
//
#include <hip/hip_runtime.h>
#include <cstdint>
#include <cstddef>

typedef unsigned short u16;
typedef unsigned int   u32;
typedef _Float16       f16;

typedef float f32x4 __attribute__((ext_vector_type(4)));
typedef _Float16 f16x8 __attribute__((ext_vector_type(8)));

#define MB (1024u*1024u)
#define RCP2048 (1.0f/2048.0f)

__device__ __forceinline__ float gelu_f(float u) {
    return 0.5f * u * (1.0f + erff(u * 0.70710678118654752f));
}

__device__ __forceinline__ void split_f(float v, f16* hi, f16* lo) {
    f16 h = (f16)v;
    *hi = h;
    *lo = (f16)((v - (float)h) * 2048.0f);
}

__device__ __forceinline__ void gload_lds16(const f16* g, f16* l) {
    __builtin_amdgcn_global_load_lds((const __attribute__((address_space(1))) u32*)(g),
                                     (__attribute__((address_space(3))) u32*)(l), 16, 0, 0);
}

// ---------------- transpose + split: in [R][C] f32 -> hi/lo fp16 [C][R] ----------------
__global__ void transpose_split_k(const float* __restrict__ in, f16* __restrict__ oh, f16* __restrict__ ol,
                                  int R, int C, long bsi, long bso) {
    __shared__ float tile[32][33];
    int z = blockIdx.z;
    in += (size_t)z * bsi; oh += (size_t)z * bso; ol += (size_t)z * bso;
    int c0 = blockIdx.x * 32, r0 = blockIdx.y * 32;
    int tx = threadIdx.x, ty = threadIdx.y;   // (32,8)
#pragma unroll
    for (int i = 0; i < 4; i++)
        tile[ty + i*8][tx] = in[(size_t)(r0 + ty + i*8) * C + c0 + tx];
    __syncthreads();
#pragma unroll
    for (int i = 0; i < 4; i++) {
        float v = tile[tx][ty + i*8];
        f16 h, l; split_f(v, &h, &l);
        size_t o = (size_t)(c0 + ty + i*8) * R + r0 + tx;
        oh[o] = h; ol[o] = l;
    }
}

// ---------------- f16 plane transpose (for V), hi+lo fused: src[t][1536] -> vt[bh][d][n] ----------------
__global__ void transpose_v_k(const f16* __restrict__ ph, const f16* __restrict__ pl,
                              f16* __restrict__ vth, f16* __restrict__ vtl) {
    __shared__ f16 th[32][33];
    __shared__ f16 tl[32][33];
    int bh = blockIdx.z; int b = bh >> 3, h = bh & 7;
    int n0 = blockIdx.x * 32, d0 = blockIdx.y * 32;
    int tx = threadIdx.x, ty = threadIdx.y;   // (32,8)
    const size_t sbase = (size_t)b * 1024 * 1536 + 1024 + h * 64;
#pragma unroll
    for (int i = 0; i < 4; i++) {
        size_t so = sbase + (size_t)(n0 + ty + i*8) * 1536 + d0 + tx;
        th[ty + i*8][tx] = ph[so];
        tl[ty + i*8][tx] = pl[so];
    }
    __syncthreads();
    const size_t dbase = (size_t)bh * 64 * 1024;
#pragma unroll
    for (int i = 0; i < 4; i++) {
        size_t do_ = dbase + (size_t)(d0 + ty + i*8) * 1024 + n0 + tx;
        vth[do_] = th[tx][ty + i*8];
        vtl[do_] = tl[tx][ty + i*8];
    }
}

// ---------------- LayerNorm: fp32 in -> optional fp32 out + hi/lo fp16 planes ----------------
template<int W32>
__global__ __launch_bounds__(256) void ln_split_k(const float* __restrict__ x, const float* __restrict__ w,
                                                  const float* __restrict__ b, float* __restrict__ o32,
                                                  f16* __restrict__ oh, f16* __restrict__ ol) {
    int t = blockIdx.x, tid = threadIdx.x;
    const float* xr = x + (size_t)t * 512;
    float v0 = xr[tid], v1 = xr[tid + 256];
    float s = v0 + v1, ss = v0*v0 + v1*v1;
#pragma unroll
    for (int m = 32; m; m >>= 1) { s += __shfl_xor(s, m); ss += __shfl_xor(ss, m); }
    __shared__ float red[8];
    int wv = tid >> 6;
    if ((tid & 63) == 0) { red[wv] = s; red[4 + wv] = ss; }
    __syncthreads();
    s  = red[0] + red[1] + red[2] + red[3];
    ss = red[4] + red[5] + red[6] + red[7];
    float mean = s * (1.f/512.f);
    float var  = ss * (1.f/512.f) - mean * mean;
    float rstd = rsqrtf(var + 1e-5f);
    float u0 = (v0 - mean) * rstd * w[tid]       + b[tid];
    float u1 = (v1 - mean) * rstd * w[tid + 256] + b[tid + 256];
    size_t base = (size_t)t * 512;
    if (W32) { o32[base + tid] = u0; o32[base + tid + 256] = u1; }
    f16 h0, l0, h1, l1;
    split_f(u0, &h0, &l0); split_f(u1, &h1, &l1);
    oh[base + tid] = h0; ol[base + tid] = l0;
    oh[base + tid + 256] = h1; ol[base + tid + 256] = l1;
}

// ---------------- plain fp32 LayerNorm (final) ----------------
__global__ __launch_bounds__(256) void ln_k(const float* __restrict__ x, const float* __restrict__ w,
                                            const float* __restrict__ b, float* __restrict__ out) {
    int t = blockIdx.x, tid = threadIdx.x;
    const float* xr = x + (size_t)t * 512;
    float v0 = xr[tid], v1 = xr[tid + 256];
    float s = v0 + v1, ss = v0*v0 + v1*v1;
#pragma unroll
    for (int m = 32; m; m >>= 1) { s += __shfl_xor(s, m); ss += __shfl_xor(ss, m); }
    __shared__ float red[8];
    int wv = tid >> 6;
    if ((tid & 63) == 0) { red[wv] = s; red[4 + wv] = ss; }
    __syncthreads();
    s  = red[0] + red[1] + red[2] + red[3];
    ss = red[4] + red[5] + red[6] + red[7];
    float mean = s * (1.f/512.f);
    float var  = ss * (1.f/512.f) - mean * mean;
    float rstd = rsqrtf(var + 1e-5f);
    out[(size_t)t*512 + tid]       = (v0 - mean) * rstd * w[tid]       + b[tid];
    out[(size_t)t*512 + tid + 256] = (v1 - mean) * rstd * w[tid + 256] + b[tid + 256];
}

// ---------------- split-fp16 MFMA GEMM: C = (Ah+Al/2048) @ (Bh+Bl/2048)^T ----------------
// A[M,K] hi/lo, Bt[N,K] hi/lo. 128x128 tile, BK=32, 3 MFMA products.
// Double-buffered LDS: stage tile k+1 while computing tile k; one barrier per K-step.
// EPI: 0 = split-store fp16 hi/lo; 1 = fp32 C += acc + bias; 2 = gelu(acc+bias) split-store;
//      3 = fp32 C = acc + bias; 4 = fp32 C += acc
template<int EPI>
__global__ __launch_bounds__(256) void gemm_sp(
    const f16* __restrict__ Ah, const f16* __restrict__ Al, int lda,
    const f16* __restrict__ Bh, const f16* __restrict__ Bl, int ldb,
    const float* __restrict__ bias,
    void* __restrict__ C0v, void* __restrict__ C1v, int ldc,
    int M, int K,
    const int* __restrict__ cnts, const int* __restrict__ offs,
    long bStrideZ, long biasStrideZ)
{
    int e = blockIdx.z;
    int mcnt = M;
    long aoff = 0;
    if (cnts) {
        mcnt = cnts[e];
        if ((int)(blockIdx.x * 128) >= mcnt) return;
        aoff = offs[e];
        Ah += (size_t)aoff * lda; Al += (size_t)aoff * lda;
        Bh += (size_t)e * bStrideZ; Bl += (size_t)e * bStrideZ;
        if (bias) bias += (size_t)e * biasStrideZ;
    } else if ((int)(blockIdx.x * 128) >= mcnt) return;

    f16*   C0h = (f16*)C0v   + (size_t)aoff * ldc;
    f16*   C1l = (f16*)C1v   + (size_t)aoff * ldc;
    float* Cf  = (float*)C0v + (size_t)aoff * ldc;

    const int m0 = blockIdx.x * 128, n0 = blockIdx.y * 128;
    const int tid  = threadIdx.x;
    const int wave = tid >> 6, lane = tid & 63;
    const int quad = lane >> 4, l15 = lane & 15;
    const int wr = (wave >> 1) * 64, wc = (wave & 1) * 64;

    __shared__ __align__(16) f16 Ash[2][4096];
    __shared__ __align__(16) f16 Asl[2][4096];
    __shared__ __align__(16) f16 Bsh[2][4096];
    __shared__ __align__(16) f16 Bsl[2][4096];

    f32x4 acc[4][4] = {};
    f32x4 ac2[4][4] = {};

    const int la = tid * 8;
    const int ra = tid >> 2, ca = (tid & 3) * 8;
    int r0a = m0 + ra;        if (r0a > mcnt - 1) r0a = mcnt - 1;
    int r1a = m0 + ra + 64;   if (r1a > mcnt - 1) r1a = mcnt - 1;
    const f16* ah0 = Ah + (size_t)r0a * lda + ca;
    const f16* ah1 = Ah + (size_t)r1a * lda + ca;
    const f16* al0 = Al + (size_t)r0a * lda + ca;
    const f16* al1 = Al + (size_t)r1a * lda + ca;
    const f16* bh0 = Bh + (size_t)(n0 + ra) * ldb + ca;
    const f16* bh1 = Bh + (size_t)(n0 + ra + 64) * ldb + ca;
    const f16* bl0 = Bl + (size_t)(n0 + ra) * ldb + ca;
    const f16* bl1 = Bl + (size_t)(n0 + ra + 64) * ldb + ca;

    auto stage = [&](int k0, int buf) {
        gload_lds16(ah0 + k0, &Ash[buf][la]);
        gload_lds16(ah1 + k0, &Ash[buf][2048 + la]);
        gload_lds16(al0 + k0, &Asl[buf][la]);
        gload_lds16(al1 + k0, &Asl[buf][2048 + la]);
        gload_lds16(bh0 + k0, &Bsh[buf][la]);
        gload_lds16(bh1 + k0, &Bsh[buf][2048 + la]);
        gload_lds16(bl0 + k0, &Bsl[buf][la]);
        gload_lds16(bl1 + k0, &Bsl[buf][2048 + la]);
    };

    stage(0, 0);
    __syncthreads();           // drains vmcnt(0): tile 0 landed

    int cur = 0;
    for (int k0 = 0; k0 < K; k0 += 32) {
        if (k0 + 32 < K) stage(k0 + 32, cur ^ 1);   // prefetch next tile (overlaps compute below)
        f16x8 afh[4], afl[4], bfh[4], bfl[4];
#pragma unroll
        for (int mi = 0; mi < 4; mi++) {
            int ro = (wr + mi*16 + l15) * 32 + quad * 8;
            afh[mi] = *(const f16x8*)&Ash[cur][ro];
            afl[mi] = *(const f16x8*)&Asl[cur][ro];
        }
#pragma unroll
        for (int ni = 0; ni < 4; ni++) {
            int ro = (wc + ni*16 + l15) * 32 + quad * 8;
            bfh[ni] = *(const f16x8*)&Bsh[cur][ro];
            bfl[ni] = *(const f16x8*)&Bsl[cur][ro];
        }
#pragma unroll
        for (int mi = 0; mi < 4; mi++)
#pragma unroll
            for (int ni = 0; ni < 4; ni++) {
                acc[mi][ni] = __builtin_amdgcn_mfma_f32_16x16x32_f16(afh[mi], bfh[ni], acc[mi][ni], 0, 0, 0);
                ac2[mi][ni] = __builtin_amdgcn_mfma_f32_16x16x32_f16(afh[mi], bfl[ni], ac2[mi][ni], 0, 0, 0);
                ac2[mi][ni] = __builtin_amdgcn_mfma_f32_16x16x32_f16(afl[mi], bfh[ni], ac2[mi][ni], 0, 0, 0);
            }
        __syncthreads();       // drains vmcnt(0) (next tile) + protects buf reuse
        cur ^= 1;
    }

#pragma unroll
    for (int mi = 0; mi < 4; mi++) {
#pragma unroll
        for (int r = 0; r < 4; r++) {
            int row = m0 + wr + mi*16 + quad*4 + r;
            if (row >= mcnt) continue;
            size_t ro = (size_t)row * ldc;
#pragma unroll
            for (int ni = 0; ni < 4; ni++) {
                int col = n0 + wc + ni*16 + l15;
                float v = acc[mi][ni][r] + ac2[mi][ni][r] * RCP2048;
                if (EPI == 0) {
                    f16 h, l; split_f(v, &h, &l);
                    C0h[ro + col] = h; C1l[ro + col] = l;
                } else if (EPI == 1) {
                    Cf[ro + col] += v + bias[col];
                } else if (EPI == 2) {
                    float g = gelu_f(v + bias[col]);
                    f16 h, l; split_f(g, &h, &l);
                    C0h[ro + col] = h; C1l[ro + col] = l;
                } else if (EPI == 3) {
                    Cf[ro + col] = v + bias[col];
                } else {
                    Cf[ro + col] += v;
                }
            }
        }
    }
}

// ---------------- split-fp16 flash attention: grid (16 q-tiles, 64 bh), block 256 ----------------
__global__ __launch_bounds__(256) void attn_sp(const f16* __restrict__ qh, const f16* __restrict__ ql,
                                               const f16* __restrict__ vth, const f16* __restrict__ vtl,
                                               f16* __restrict__ oh, f16* __restrict__ ol) {
    const int qt = blockIdx.x;
    const int bh = blockIdx.y;
    const int b = bh >> 3, h = bh & 7;
    const int tid = threadIdx.x;
    const int wave = tid >> 6, lane = tid & 63;
    const int quad = lane >> 4, l15 = lane & 15;

    __shared__ __align__(16) f16 Ksh[4096];   // [64 kv][64 d] hi, swizzled
    __shared__ __align__(16) f16 Ksl[4096];   // lo
    __shared__ __align__(16) f16 Vsh[4096];   // [64 d][64 kv] hi, swizzled
    __shared__ __align__(16) f16 Vsl[4096];   // lo
    __shared__ __align__(16) f16 Ph[4][16][80];
    __shared__ __align__(16) f16 Pl[4][16][80];

    const size_t tq = (size_t)b * 1024 + qt * 64 + wave * 16 + l15;
    f16x8 qh0 = *(const f16x8*)&qh[tq * 1536 + h * 64 + quad * 8];
    f16x8 qh1 = *(const f16x8*)&qh[tq * 1536 + h * 64 + 32 + quad * 8];
    f16x8 ql0 = *(const f16x8*)&ql[tq * 1536 + h * 64 + quad * 8];
    f16x8 ql1 = *(const f16x8*)&ql[tq * 1536 + h * 64 + 32 + quad * 8];

    f32x4 ao[4] = {}, ao2[4] = {};
    float m_i[4] = {-INFINITY, -INFINITY, -INFINITY, -INFINITY};
    float l_i[4] = {0.f, 0.f, 0.f, 0.f};

    const f16* kbh = qh + (size_t)b * 1024 * 1536 + 512 + h * 64;
    const f16* kbl = ql + (size_t)b * 1024 * 1536 + 512 + h * 64;
    const f16* vbh = vth + (size_t)bh * 64 * 1024;
    const f16* vbl = vtl + (size_t)bh * 64 * 1024;

    const int c0 = tid,       r0 = c0 >> 3, g0 = ((c0 & 7) ^ (r0 & 7)) * 8;
    const int c1 = tid + 256, r1 = c1 >> 3, g1 = ((c1 & 7) ^ (r1 & 7)) * 8;
    const int ko0 = r0 * 1536 + g0, ko1 = r1 * 1536 + g1;   // K: row stride 1536 f16
    const int vo0 = r0 * 1024 + g0, vo1 = r1 * 1024 + g1;   // V^T: row stride 1024 f16

    for (int kv0 = 0; kv0 < 1024; kv0 += 64) {
        __syncthreads();   // previous iteration's LDS reads complete before overwrite
        {
            const size_t kadv = (size_t)kv0 * 1536;
            gload_lds16(kbh + kadv + ko0, &Ksh[c0 * 8]);
            gload_lds16(kbh + kadv + ko1, &Ksh[c1 * 8]);
            gload_lds16(kbl + kadv + ko0, &Ksl[c0 * 8]);
            gload_lds16(kbl + kadv + ko1, &Ksl[c1 * 8]);
            gload_lds16(vbh + kv0 + vo0, &Vsh[c0 * 8]);
            gload_lds16(vbh + kv0 + vo1, &Vsh[c1 * 8]);
            gload_lds16(vbl + kv0 + vo0, &Vsl[c0 * 8]);
            gload_lds16(vbl + kv0 + vo1, &Vsl[c1 * 8]);
        }
        __syncthreads();   // drains vmcnt(0): tiles landed for all waves

        f32x4 sa[4] = {}, sa2[4] = {};
        const int sw = l15 & 7;
#pragma unroll
        for (int ni = 0; ni < 4; ni++) {
            const int kb = (ni*16 + l15) * 64;
            f16x8 kh0 = *(const f16x8*)&Ksh[kb + ((quad       ^ sw) << 3)];
            f16x8 kh1 = *(const f16x8*)&Ksh[kb + (((quad + 4) ^ sw) << 3)];
            f16x8 kl0 = *(const f16x8*)&Ksl[kb + ((quad       ^ sw) << 3)];
            f16x8 kl1 = *(const f16x8*)&Ksl[kb + (((quad + 4) ^ sw) << 3)];
            sa[ni]  = __builtin_amdgcn_mfma_f32_16x16x32_f16(qh0, kh0, sa[ni], 0, 0, 0);
            sa[ni]  = __builtin_amdgcn_mfma_f32_16x16x32_f16(qh1, kh1, sa[ni], 0, 0, 0);
            sa2[ni] = __builtin_amdgcn_mfma_f32_16x16x32_f16(qh0, kl0, sa2[ni], 0, 0, 0);
            sa2[ni] = __builtin_amdgcn_mfma_f32_16x16x32_f16(qh1, kl1, sa2[ni], 0, 0, 0);
            sa2[ni] = __builtin_amdgcn_mfma_f32_16x16x32_f16(ql0, kh0, sa2[ni], 0, 0, 0);
            sa2[ni] = __builtin_amdgcn_mfma_f32_16x16x32_f16(ql1, kh1, sa2[ni], 0, 0, 0);
        }
        float alpha[4];
#pragma unroll
        for (int r = 0; r < 4; r++) {
            float s0 = (sa[0][r] + sa2[0][r]*RCP2048) * 0.125f;
            float s1 = (sa[1][r] + sa2[1][r]*RCP2048) * 0.125f;
            float s2 = (sa[2][r] + sa2[2][r]*RCP2048) * 0.125f;
            float s3 = (sa[3][r] + sa2[3][r]*RCP2048) * 0.125f;
            float mx = fmaxf(fmaxf(s0, s1), fmaxf(s2, s3));
#pragma unroll
            for (int msk = 1; msk < 16; msk <<= 1) mx = fmaxf(mx, __shfl_xor(mx, msk));
            float mnew = fmaxf(m_i[r], mx);
            alpha[r] = __expf(m_i[r] - mnew);
            float p0 = __expf(s0 - mnew), p1 = __expf(s1 - mnew);
            float p2 = __expf(s2 - mnew), p3 = __expf(s3 - mnew);
            sa[0][r] = p0; sa[1][r] = p1; sa[2][r] = p2; sa[3][r] = p3;
            float sum = p0 + p1 + p2 + p3;
#pragma unroll
            for (int msk = 1; msk < 16; msk <<= 1) sum += __shfl_xor(sum, msk);
            l_i[r] = l_i[r] * alpha[r] + sum;
            m_i[r] = mnew;
        }
#pragma unroll
        for (int ni = 0; ni < 4; ni++)
#pragma unroll
            for (int r = 0; r < 4; r++) {
                f16 hh, ll; split_f(sa[ni][r], &hh, &ll);
                Ph[wave][quad*4 + r][ni*16 + l15] = hh;
                Pl[wave][quad*4 + r][ni*16 + l15] = ll;
            }
#pragma unroll
        for (int di = 0; di < 4; di++)
#pragma unroll
            for (int r = 0; r < 4; r++) { ao[di][r] *= alpha[r]; ao2[di][r] *= alpha[r]; }
        f16x8 pfh0 = *(const f16x8*)&Ph[wave][l15][quad * 8];
        f16x8 pfh1 = *(const f16x8*)&Ph[wave][l15][32 + quad * 8];
        f16x8 pfl0 = *(const f16x8*)&Pl[wave][l15][quad * 8];
        f16x8 pfl1 = *(const f16x8*)&Pl[wave][l15][32 + quad * 8];
#pragma unroll
        for (int di = 0; di < 4; di++) {
            const int vb = (di*16 + l15) * 64;
            f16x8 vh0 = *(const f16x8*)&Vsh[vb + ((quad       ^ sw) << 3)];
            f16x8 vh1 = *(const f16x8*)&Vsh[vb + (((quad + 4) ^ sw) << 3)];
            f16x8 vl0 = *(const f16x8*)&Vsl[vb + ((quad       ^ sw) << 3)];
            f16x8 vl1 = *(const f16x8*)&Vsl[vb + (((quad + 4) ^ sw) << 3)];
            ao[di]  = __builtin_amdgcn_mfma_f32_16x16x32_f16(pfh0, vh0, ao[di], 0, 0, 0);
            ao[di]  = __builtin_amdgcn_mfma_f32_16x16x32_f16(pfh1, vh1, ao[di], 0, 0, 0);
            ao2[di] = __builtin_amdgcn_mfma_f32_16x16x32_f16(pfh0, vl0, ao2[di], 0, 0, 0);
            ao2[di] = __builtin_amdgcn_mfma_f32_16x16x32_f16(pfh1, vl1, ao2[di], 0, 0, 0);
            ao2[di] = __builtin_amdgcn_mfma_f32_16x16x32_f16(pfl0, vh0, ao2[di], 0, 0, 0);
            ao2[di] = __builtin_amdgcn_mfma_f32_16x16x32_f16(pfl1, vh1, ao2[di], 0, 0, 0);
        }
    }
#pragma unroll
    for (int di = 0; di < 4; di++) {
#pragma unroll
        for (int r = 0; r < 4; r++) {
            size_t t = (size_t)b * 1024 + qt * 64 + wave * 16 + quad * 4 + r;
            float v = (ao[di][r] + ao2[di][r] * RCP2048) / l_i[r];
            f16 hh, ll; split_f(v, &hh, &ll);
            oh[t * 512 + h * 64 + di * 16 + l15] = hh;
            ol[t * 512 + h * 64 + di * 16 + l15] = ll;
        }
    }
}

// ---------------- gating (fp32, no atomics) ----------------
__global__ __launch_bounds__(64) void gating_k(const float* __restrict__ xn, const float* __restrict__ wg,
                                               int* __restrict__ top_i, float* __restrict__ top_g) {
    int t = blockIdx.x, lane = threadIdx.x;
    const float* xr = xn + (size_t)t * 512;
    float acc[8] = {};
#pragma unroll
    for (int i = 0; i < 8; i++) {
        int d = lane + i*64;
        float xv = xr[d];
        const float* wrow = wg + (size_t)d * 8;
#pragma unroll
        for (int e = 0; e < 8; e++) acc[e] += xv * wrow[e];
    }
#pragma unroll
    for (int e = 0; e < 8; e++)
#pragma unroll
        for (int m = 32; m; m >>= 1) acc[e] += __shfl_xor(acc[e], m);
    if (lane == 0) {
        int e0 = 0; float v0 = acc[0];
        for (int e = 1; e < 8; e++) if (acc[e] > v0) { v0 = acc[e]; e0 = e; }
        int e1 = -1; float v1 = -INFINITY;
        for (int e = 0; e < 8; e++) if (e != e0 && acc[e] > v1) { v1 = acc[e]; e1 = e; }
        float g0 = 1.f / (1.f + expf(v1 - v0));
        top_i[2*t] = e0; top_i[2*t + 1] = e1;
        top_g[2*t] = g0; top_g[2*t + 1] = 1.f - g0;
    }
}

// ---------------- fused routing: histogram + offsets in one single-block kernel ----------------
__global__ __launch_bounds__(1024) void route_k(const int* __restrict__ top_i, int* __restrict__ counts,
                                                int* __restrict__ offs, int* __restrict__ cursor) {
    __shared__ int lc[8];
    int tid = threadIdx.x;
    if (tid < 8) lc[tid] = 0;
    __syncthreads();
    const int4* p = (const int4*)top_i;          // 16384 ints = 4096 int4
#pragma unroll
    for (int i = 0; i < 4; i++) {
        int4 v = p[tid + i*1024];
        atomicAdd(&lc[v.x], 1); atomicAdd(&lc[v.y], 1);
        atomicAdd(&lc[v.z], 1); atomicAdd(&lc[v.w], 1);
    }
    __syncthreads();
    if (tid == 0) {
        int o = 0;
        for (int e = 0; e < 8; e++) { int c = lc[e]; counts[e] = c; offs[e] = o; cursor[e] = o; o += c; }
    }
}

// ---------------- scatter: per-block LDS ranks + 8 global atomics per block ----------------
__global__ __launch_bounds__(256) void scatter_k(const int* __restrict__ top_i, int* __restrict__ cursor,
                                                 int* __restrict__ assign_token, int* __restrict__ assign_slot) {
    __shared__ int lcnt[8];
    __shared__ int base[8];
    int tid = threadIdx.x;
    int t = blockIdx.x * 256 + tid;
    if (tid < 8) lcnt[tid] = 0;
    __syncthreads();
    int e0 = top_i[2*t], e1 = top_i[2*t + 1];
    int r0 = atomicAdd(&lcnt[e0], 1);
    int r1 = atomicAdd(&lcnt[e1], 1);
    __syncthreads();
    if (tid < 8) base[tid] = atomicAdd(&cursor[tid], lcnt[tid]);
    __syncthreads();
    int p0 = base[e0] + r0, p1 = base[e1] + r1;
    assign_token[p0] = t; assign_slot[2*t]     = p0;
    assign_token[p1] = t; assign_slot[2*t + 1] = p1;
}

__global__ __launch_bounds__(64) void gather2_k(const f16* __restrict__ xh, const f16* __restrict__ xl,
                                                const int* __restrict__ assign_token,
                                                f16* __restrict__ oh, f16* __restrict__ ol) {
    int a = blockIdx.x, lane = threadIdx.x;
    int t = assign_token[a];
    ((uint4*)(oh + (size_t)a * 512))[lane] = ((const uint4*)(xh + (size_t)t * 512))[lane];
    ((uint4*)(ol + (size_t)a * 512))[lane] = ((const uint4*)(xl + (size_t)t * 512))[lane];
}

__global__ __launch_bounds__(64) void combine_k(float* __restrict__ x, const float* __restrict__ y,
                                                const int* __restrict__ assign_slot, const float* __restrict__ top_g) {
    int t = blockIdx.x, lane = threadIdx.x;
    int p0 = assign_slot[2*t], p1 = assign_slot[2*t + 1];
    float g0 = top_g[2*t], g1 = top_g[2*t + 1];
    float4* xr = (float4*)(x + (size_t)t * 512);
    const float4* y0 = (const float4*)(y + (size_t)p0 * 512);
    const float4* y1 = (const float4*)(y + (size_t)p1 * 512);
#pragma unroll
    for (int i = 0; i < 2; i++) {
        int idx = lane + i * 64;
        float4 a = xr[idx], c0 = y0[idx], c1 = y1[idx];
        a.x += g0*c0.x + g1*c1.x; a.y += g0*c0.y + g1*c1.y;
        a.z += g0*c0.z + g1*c1.z; a.w += g0*c0.w + g1*c1.w;
        xr[idx] = a;
    }
}

extern "C" void kernel_launch(void* const* d_in, const int* in_sizes, int n_in,
                              void* d_out, int out_size, void* d_ws, size_t ws_size,
                              hipStream_t stream) {
    const float* x_in = (const float*)d_in[0];
    const float* ln1w = (const float*)d_in[1];
    const float* ln1b = (const float*)d_in[2];
    const float* qkvw = (const float*)d_in[3];
    const float* outw = (const float*)d_in[4];
    const float* outb = (const float*)d_in[5];
    const float* ln2w = (const float*)d_in[6];
    const float* ln2b = (const float*)d_in[7];
    const float* wg   = (const float*)d_in[8];
    const float* ew1  = (const float*)d_in[9];
    const float* eb1  = (const float*)d_in[10];
    const float* ew2  = (const float*)d_in[11];
    const float* eb2  = (const float*)d_in[12];
    const float* flnw = (const float*)d_in[13];
    const float* flnb = (const float*)d_in[14];

    float* x = (float*)d_out;                         // residual [8192,512] f32

    char* ws = (char*)d_ws;
    float* xn32  = (float*)(ws + 0);                  // 16 MB (dead after gating)
    f16*   xnh   = (f16*)(ws + 16*MB);                //  8 MB (dead after gather2)
    f16*   xnl   = (f16*)(ws + 24*MB);                //  8 MB
    f16*   qkTh  = (f16*)(ws + 32*MB);                //  1.5 MB
    f16*   qkTl  = (f16*)(ws + 34*MB);
    f16*   outTh = (f16*)(ws + 36*MB);                //  0.5 MB
    f16*   outTl = (f16*)(ws + 37*MB);
    f16*   w1Th  = (f16*)(ws + 38*MB);                // 16 MB [8][2048][512]
    f16*   w1Tl  = (f16*)(ws + 54*MB);
    f16*   w2Th  = (f16*)(ws + 70*MB);                // 16 MB [8][512][2048]
    f16*   w2Tl  = (f16*)(ws + 86*MB);
    char*  S     = ws + 102*MB;                       // 96 MB scratch
    // attn phase
    f16*   qbh   = (f16*)(S + 0);                     // 24 MB [8192,1536]
    f16*   qbl   = (f16*)(S + 24*MB);
    f16*   vth   = (f16*)(S + 48*MB);                 //  8 MB [64][64][1024]
    f16*   vtl   = (f16*)(S + 56*MB);
    f16*   obh   = (f16*)(S + 64*MB);                 //  8 MB [8192,512]
    f16*   obl   = (f16*)(S + 72*MB);
    // moe phase (reuses S + dead ws+0..32 region)
    f16*   xeh   = (f16*)(S + 0);                     // 16 MB [16384,512]
    f16*   xel   = (f16*)(S + 16*MB);
    f16*   hbh   = (f16*)(S + 32*MB);                 // 32 MB [16384,1024] per N-slice
    f16*   hbl   = (f16*)(S + 64*MB);                 // 32 MB
    float* ybuf  = (float*)(ws + 0);                  // 32 MB [16384,512] (over xn32/xnh/xnl, dead by then)
    char*  SM    = ws + 198*MB;
    int*   top_i        = (int*)(SM + 0);
    float* top_g        = (float*)(SM + 65536);
    int*   assign_token = (int*)(SM + 131072);
    int*   assign_slot  = (int*)(SM + 196608);
    int*   counts       = (int*)(SM + 262144);
    int*   offs         = (int*)(SM + 262400);
    int*   cursor       = (int*)(SM + 262656);

    hipMemcpyAsync(x, x_in, (size_t)8192 * 512 * 4, hipMemcpyDeviceToDevice, stream);

    dim3 tb(32, 8);
    for (int l = 0; l < 4; l++) {
        const float* qkvw_l = qkvw + (size_t)l * 512 * 1536;
        const float* outw_l = outw + (size_t)l * 512 * 512;
        const float* ew1_l  = ew1  + (size_t)l * 8 * 512 * 2048;
        const float* ew2_l  = ew2  + (size_t)l * 8 * 2048 * 512;
        const float* eb1_l  = eb1  + (size_t)l * 8 * 2048;
        const float* eb2_l  = eb2  + (size_t)l * 8 * 512;

        // weight prep: transpose + split to fp16 hi/lo, [N,K] layout
        transpose_split_k<<<dim3(48, 16, 1), tb, 0, stream>>>(qkvw_l, qkTh, qkTl, 512, 1536, 0, 0);
        transpose_split_k<<<dim3(16, 16, 1), tb, 0, stream>>>(outw_l, outTh, outTl, 512, 512, 0, 0);
        transpose_split_k<<<dim3(64, 16, 8), tb, 0, stream>>>(ew1_l, w1Th, w1Tl, 512, 2048,
                                                              (long)512*2048, (long)512*2048);
        transpose_split_k<<<dim3(16, 64, 8), tb, 0, stream>>>(ew2_l, w2Th, w2Tl, 2048, 512,
                                                              (long)2048*512, (long)2048*512);

        // ---- attention ----
        ln_split_k<0><<<8192, 256, 0, stream>>>(x, ln1w + l*512, ln1b + l*512, nullptr, xnh, xnl);
        gemm_sp<0><<<dim3(64, 12, 1), 256, 0, stream>>>(xnh, xnl, 512, qkTh, qkTl, 512, nullptr,
                                                        qbh, qbl, 1536, 8192, 512,
                                                        nullptr, nullptr, 0, 0);
        transpose_v_k<<<dim3(32, 2, 64), tb, 0, stream>>>(qbh, qbl, vth, vtl);
        attn_sp<<<dim3(16, 64), 256, 0, stream>>>(qbh, qbl, vth, vtl, obh, obl);
        gemm_sp<1><<<dim3(64, 4, 1), 256, 0, stream>>>(obh, obl, 512, outTh, outTl, 512, outb + l*512,
                                                       x, nullptr, 512, 8192, 512,
                                                       nullptr, nullptr, 0, 0);

        // ---- MoE ----
        ln_split_k<1><<<8192, 256, 0, stream>>>(x, ln2w + l*512, ln2b + l*512, xn32, xnh, xnl);
        gating_k<<<8192, 64, 0, stream>>>(xn32, wg + (size_t)l*512*8, top_i, top_g);
        route_k<<<1, 1024, 0, stream>>>(top_i, counts, offs, cursor);
        scatter_k<<<32, 256, 0, stream>>>(top_i, cursor, assign_token, assign_slot);
        gather2_k<<<16384, 64, 0, stream>>>(xnh, xnl, assign_token, xeh, xel);

        for (int s = 0; s < 2; s++) {
            const f16* b1h = w1Th + (size_t)s * 1024 * 512;   // rows s*1024.. of [2048,512]
            const f16* b1l = w1Tl + (size_t)s * 1024 * 512;
            const f16* b2h = w2Th + (size_t)s * 1024;         // k-cols s*1024.. of [512,2048]
            const f16* b2l = w2Tl + (size_t)s * 1024;
            // h = gelu(xe @ w1_slice + b1): M=16384 (per-expert), N=1024, K=512
            gemm_sp<2><<<dim3(64, 8, 8), 256, 0, stream>>>(xeh, xel, 512, b1h, b1l, 512, eb1_l + s*1024,
                                                           hbh, hbl, 1024, 0, 512,
                                                           counts, offs, (long)2048*512, 2048);
            // y (+)= h @ w2_kslice: M=16384, N=512, K=1024
            if (s == 0)
                gemm_sp<3><<<dim3(64, 4, 8), 256, 0, stream>>>(hbh, hbl, 1024, b2h, b2l, 2048, eb2_l,
                                                               ybuf, nullptr, 512, 0, 1024,
                                                               counts, offs, (long)512*2048, 512);
            else
                gemm_sp<4><<<dim3(64, 4, 8), 256, 0, stream>>>(hbh, hbl, 1024, b2h, b2l, 2048, nullptr,
                                                               ybuf, nullptr, 512, 0, 1024,
                                                               counts, offs, (long)512*2048, 512);
        }
        combine_k<<<8192, 64, 0, stream>>>(x, ybuf, assign_slot, top_g);
    }
    ln_k<<<8192, 256, 0, stream>>>(x, flnw, flnb, x);
}

// Round 5
// 3797.787 us; speedup vs baseline: 1.8544x; 1.2987x over previous
//
#include <hip/hip_runtime.h>
#include <cstdint>
#include <cstddef>

typedef unsigned short u16;
typedef unsigned int   u32;
typedef _Float16       f16;

typedef float f32x4 __attribute__((ext_vector_type(4)));
typedef _Float16 f16x8 __attribute__((ext_vector_type(8)));

#define MB (1024u*1024u)
#define RCP2048 (1.0f/2048.0f)

__device__ __forceinline__ float gelu_f(float u) {
    return 0.5f * u * (1.0f + erff(u * 0.70710678118654752f));
}

__device__ __forceinline__ void split_f(float v, f16* hi, f16* lo) {
    f16 h = (f16)v;
    *hi = h;
    *lo = (f16)((v - (float)h) * 2048.0f);
}

__device__ __forceinline__ void gload_lds16(const f16* g, f16* l) {
    __builtin_amdgcn_global_load_lds((const __attribute__((address_space(1))) u32*)(g),
                                     (__attribute__((address_space(3))) u32*)(l), 16, 0, 0);
}

// ---------------- transpose + split: in [R][C] f32 -> hi/lo fp16 [C][R] ----------------
__global__ void transpose_split_k(const float* __restrict__ in, f16* __restrict__ oh, f16* __restrict__ ol,
                                  int R, int C, long bsi, long bso) {
    __shared__ float tile[32][33];
    int z = blockIdx.z;
    in += (size_t)z * bsi; oh += (size_t)z * bso; ol += (size_t)z * bso;
    int c0 = blockIdx.x * 32, r0 = blockIdx.y * 32;
    int tx = threadIdx.x, ty = threadIdx.y;   // (32,8)
#pragma unroll
    for (int i = 0; i < 4; i++)
        tile[ty + i*8][tx] = in[(size_t)(r0 + ty + i*8) * C + c0 + tx];
    __syncthreads();
#pragma unroll
    for (int i = 0; i < 4; i++) {
        float v = tile[tx][ty + i*8];
        f16 h, l; split_f(v, &h, &l);
        size_t o = (size_t)(c0 + ty + i*8) * R + r0 + tx;
        oh[o] = h; ol[o] = l;
    }
}

// ---------------- f16 plane transpose (for V), hi+lo fused: src[t][1536] -> vt[bh][d][n] ----------------
__global__ void transpose_v_k(const f16* __restrict__ ph, const f16* __restrict__ pl,
                              f16* __restrict__ vth, f16* __restrict__ vtl) {
    __shared__ f16 th[32][33];
    __shared__ f16 tl[32][33];
    int bh = blockIdx.z; int b = bh >> 3, h = bh & 7;
    int n0 = blockIdx.x * 32, d0 = blockIdx.y * 32;
    int tx = threadIdx.x, ty = threadIdx.y;   // (32,8)
    const size_t sbase = (size_t)b * 1024 * 1536 + 1024 + h * 64;
#pragma unroll
    for (int i = 0; i < 4; i++) {
        size_t so = sbase + (size_t)(n0 + ty + i*8) * 1536 + d0 + tx;
        th[ty + i*8][tx] = ph[so];
        tl[ty + i*8][tx] = pl[so];
    }
    __syncthreads();
    const size_t dbase = (size_t)bh * 64 * 1024;
#pragma unroll
    for (int i = 0; i < 4; i++) {
        size_t do_ = dbase + (size_t)(d0 + ty + i*8) * 1024 + n0 + tx;
        vth[do_] = th[tx][ty + i*8];
        vtl[do_] = tl[tx][ty + i*8];
    }
}

// ---------------- LayerNorm: fp32 in -> optional fp32 out + hi/lo fp16 planes ----------------
template<int W32>
__global__ __launch_bounds__(256) void ln_split_k(const float* __restrict__ x, const float* __restrict__ w,
                                                  const float* __restrict__ b, float* __restrict__ o32,
                                                  f16* __restrict__ oh, f16* __restrict__ ol) {
    int t = blockIdx.x, tid = threadIdx.x;
    const float* xr = x + (size_t)t * 512;
    float v0 = xr[tid], v1 = xr[tid + 256];
    float s = v0 + v1, ss = v0*v0 + v1*v1;
#pragma unroll
    for (int m = 32; m; m >>= 1) { s += __shfl_xor(s, m); ss += __shfl_xor(ss, m); }
    __shared__ float red[8];
    int wv = tid >> 6;
    if ((tid & 63) == 0) { red[wv] = s; red[4 + wv] = ss; }
    __syncthreads();
    s  = red[0] + red[1] + red[2] + red[3];
    ss = red[4] + red[5] + red[6] + red[7];
    float mean = s * (1.f/512.f);
    float var  = ss * (1.f/512.f) - mean * mean;
    float rstd = rsqrtf(var + 1e-5f);
    float u0 = (v0 - mean) * rstd * w[tid]       + b[tid];
    float u1 = (v1 - mean) * rstd * w[tid + 256] + b[tid + 256];
    size_t base = (size_t)t * 512;
    if (W32) { o32[base + tid] = u0; o32[base + tid + 256] = u1; }
    f16 h0, l0, h1, l1;
    split_f(u0, &h0, &l0); split_f(u1, &h1, &l1);
    oh[base + tid] = h0; ol[base + tid] = l0;
    oh[base + tid + 256] = h1; ol[base + tid + 256] = l1;
}

// ---------------- plain fp32 LayerNorm (final) ----------------
__global__ __launch_bounds__(256) void ln_k(const float* __restrict__ x, const float* __restrict__ w,
                                            const float* __restrict__ b, float* __restrict__ out) {
    int t = blockIdx.x, tid = threadIdx.x;
    const float* xr = x + (size_t)t * 512;
    float v0 = xr[tid], v1 = xr[tid + 256];
    float s = v0 + v1, ss = v0*v0 + v1*v1;
#pragma unroll
    for (int m = 32; m; m >>= 1) { s += __shfl_xor(s, m); ss += __shfl_xor(ss, m); }
    __shared__ float red[8];
    int wv = tid >> 6;
    if ((tid & 63) == 0) { red[wv] = s; red[4 + wv] = ss; }
    __syncthreads();
    s  = red[0] + red[1] + red[2] + red[3];
    ss = red[4] + red[5] + red[6] + red[7];
    float mean = s * (1.f/512.f);
    float var  = ss * (1.f/512.f) - mean * mean;
    float rstd = rsqrtf(var + 1e-5f);
    out[(size_t)t*512 + tid]       = (v0 - mean) * rstd * w[tid]       + b[tid];
    out[(size_t)t*512 + tid + 256] = (v1 - mean) * rstd * w[tid + 256] + b[tid + 256];
}

// ---------------- split-fp16 MFMA GEMM: C = (Ah+Al/2048) @ (Bh+Bl/2048)^T ----------------
// A[M,K] hi/lo, Bt[N,K] hi/lo. 128x128 tile, BK=32, 3 MFMA products. Double-buffered LDS.
// 1D grid + in-kernel XCD-locality decode (wgid%8 ~ XCD):
//   MoE (cnts!=null): e = wg&7  -> expert e pinned to XCD e; per-XCD: B-slice L2-resident,
//                     A-panel reused across consecutive y (y fastest within x).
//   dense:            xcd = wg&7 owns x-chunk [xcd*nx/8, ..+nx/8); y outer, x inner.
// EPI: 0 = split-store fp16 hi/lo; 1 = fp32 C += acc + bias; 2 = gelu(acc+bias) split-store;
//      3 = fp32 C = acc + bias; 4 = fp32 C += acc
template<int EPI>
__global__ __launch_bounds__(256) void gemm_sp(
    const f16* __restrict__ Ah, const f16* __restrict__ Al, int lda,
    const f16* __restrict__ Bh, const f16* __restrict__ Bl, int ldb,
    const float* __restrict__ bias,
    void* __restrict__ C0v, void* __restrict__ C1v, int ldc,
    int M, int K, int nx, int ny,
    const int* __restrict__ cnts, const int* __restrict__ offs,
    long bStrideZ, long biasStrideZ)
{
    int bx, by, e;
    {
        int wg = blockIdx.x;
        if (cnts) {
            e = wg & 7;
            int s = wg >> 3;
            by = s % ny;          // y fastest: consecutive same-XCD blocks share the A panel
            bx = s / ny;
        } else {
            int xcd = wg & 7;
            int s = wg >> 3;
            int nxc = nx >> 3;
            bx = xcd * nxc + (s % nxc);   // XCD owns a contiguous x-chunk
            by = s / nxc;                 // y outer: B panel streams, A chunk resident
            e = 0;
        }
    }

    int mcnt = M;
    long aoff = 0;
    if (cnts) {
        mcnt = cnts[e];
        if (bx * 128 >= mcnt) return;
        aoff = offs[e];
        Ah += (size_t)aoff * lda; Al += (size_t)aoff * lda;
        Bh += (size_t)e * bStrideZ; Bl += (size_t)e * bStrideZ;
        if (bias) bias += (size_t)e * biasStrideZ;
    } else if (bx * 128 >= mcnt) return;

    f16*   C0h = (f16*)C0v   + (size_t)aoff * ldc;
    f16*   C1l = (f16*)C1v   + (size_t)aoff * ldc;
    float* Cf  = (float*)C0v + (size_t)aoff * ldc;

    const int m0 = bx * 128, n0 = by * 128;
    const int tid  = threadIdx.x;
    const int wave = tid >> 6, lane = tid & 63;
    const int quad = lane >> 4, l15 = lane & 15;
    const int wr = (wave >> 1) * 64, wc = (wave & 1) * 64;

    __shared__ __align__(16) f16 Ash[2][4096];
    __shared__ __align__(16) f16 Asl[2][4096];
    __shared__ __align__(16) f16 Bsh[2][4096];
    __shared__ __align__(16) f16 Bsl[2][4096];

    f32x4 acc[4][4] = {};
    f32x4 ac2[4][4] = {};

    const int la = tid * 8;
    const int ra = tid >> 2, ca = (tid & 3) * 8;
    int r0a = m0 + ra;        if (r0a > mcnt - 1) r0a = mcnt - 1;
    int r1a = m0 + ra + 64;   if (r1a > mcnt - 1) r1a = mcnt - 1;
    const f16* ah0 = Ah + (size_t)r0a * lda + ca;
    const f16* ah1 = Ah + (size_t)r1a * lda + ca;
    const f16* al0 = Al + (size_t)r0a * lda + ca;
    const f16* al1 = Al + (size_t)r1a * lda + ca;
    const f16* bh0 = Bh + (size_t)(n0 + ra) * ldb + ca;
    const f16* bh1 = Bh + (size_t)(n0 + ra + 64) * ldb + ca;
    const f16* bl0 = Bl + (size_t)(n0 + ra) * ldb + ca;
    const f16* bl1 = Bl + (size_t)(n0 + ra + 64) * ldb + ca;

    auto stage = [&](int k0, int buf) {
        gload_lds16(ah0 + k0, &Ash[buf][la]);
        gload_lds16(ah1 + k0, &Ash[buf][2048 + la]);
        gload_lds16(al0 + k0, &Asl[buf][la]);
        gload_lds16(al1 + k0, &Asl[buf][2048 + la]);
        gload_lds16(bh0 + k0, &Bsh[buf][la]);
        gload_lds16(bh1 + k0, &Bsh[buf][2048 + la]);
        gload_lds16(bl0 + k0, &Bsl[buf][la]);
        gload_lds16(bl1 + k0, &Bsl[buf][2048 + la]);
    };

    stage(0, 0);
    __syncthreads();           // drains vmcnt(0): tile 0 landed

    int cur = 0;
    for (int k0 = 0; k0 < K; k0 += 32) {
        if (k0 + 32 < K) stage(k0 + 32, cur ^ 1);   // prefetch next tile (overlaps compute below)
        f16x8 afh[4], afl[4], bfh[4], bfl[4];
#pragma unroll
        for (int mi = 0; mi < 4; mi++) {
            int ro = (wr + mi*16 + l15) * 32 + quad * 8;
            afh[mi] = *(const f16x8*)&Ash[cur][ro];
            afl[mi] = *(const f16x8*)&Asl[cur][ro];
        }
#pragma unroll
        for (int ni = 0; ni < 4; ni++) {
            int ro = (wc + ni*16 + l15) * 32 + quad * 8;
            bfh[ni] = *(const f16x8*)&Bsh[cur][ro];
            bfl[ni] = *(const f16x8*)&Bsl[cur][ro];
        }
#pragma unroll
        for (int mi = 0; mi < 4; mi++)
#pragma unroll
            for (int ni = 0; ni < 4; ni++) {
                acc[mi][ni] = __builtin_amdgcn_mfma_f32_16x16x32_f16(afh[mi], bfh[ni], acc[mi][ni], 0, 0, 0);
                ac2[mi][ni] = __builtin_amdgcn_mfma_f32_16x16x32_f16(afh[mi], bfl[ni], ac2[mi][ni], 0, 0, 0);
                ac2[mi][ni] = __builtin_amdgcn_mfma_f32_16x16x32_f16(afl[mi], bfh[ni], ac2[mi][ni], 0, 0, 0);
            }
        __syncthreads();       // drains vmcnt(0) (next tile) + protects buf reuse
        cur ^= 1;
    }

#pragma unroll
    for (int mi = 0; mi < 4; mi++) {
#pragma unroll
        for (int r = 0; r < 4; r++) {
            int row = m0 + wr + mi*16 + quad*4 + r;
            if (row >= mcnt) continue;
            size_t ro = (size_t)row * ldc;
#pragma unroll
            for (int ni = 0; ni < 4; ni++) {
                int col = n0 + wc + ni*16 + l15;
                float v = acc[mi][ni][r] + ac2[mi][ni][r] * RCP2048;
                if (EPI == 0) {
                    f16 h, l; split_f(v, &h, &l);
                    C0h[ro + col] = h; C1l[ro + col] = l;
                } else if (EPI == 1) {
                    Cf[ro + col] += v + bias[col];
                } else if (EPI == 2) {
                    float g = gelu_f(v + bias[col]);
                    f16 h, l; split_f(g, &h, &l);
                    C0h[ro + col] = h; C1l[ro + col] = l;
                } else if (EPI == 3) {
                    Cf[ro + col] = v + bias[col];
                } else {
                    Cf[ro + col] += v;
                }
            }
        }
    }
}

// ---------------- split-fp16 flash attention: grid (16 q-tiles, 64 bh), block 256 ----------------
__global__ __launch_bounds__(256) void attn_sp(const f16* __restrict__ qh, const f16* __restrict__ ql,
                                               const f16* __restrict__ vth, const f16* __restrict__ vtl,
                                               f16* __restrict__ oh, f16* __restrict__ ol) {
    const int qt = blockIdx.x;
    const int bh = blockIdx.y;
    const int b = bh >> 3, h = bh & 7;
    const int tid = threadIdx.x;
    const int wave = tid >> 6, lane = tid & 63;
    const int quad = lane >> 4, l15 = lane & 15;

    __shared__ __align__(16) f16 Ksh[4096];   // [64 kv][64 d] hi, swizzled
    __shared__ __align__(16) f16 Ksl[4096];   // lo
    __shared__ __align__(16) f16 Vsh[4096];   // [64 d][64 kv] hi, swizzled
    __shared__ __align__(16) f16 Vsl[4096];   // lo
    __shared__ __align__(16) f16 Ph[4][16][80];
    __shared__ __align__(16) f16 Pl[4][16][80];

    const size_t tq = (size_t)b * 1024 + qt * 64 + wave * 16 + l15;
    f16x8 qh0 = *(const f16x8*)&qh[tq * 1536 + h * 64 + quad * 8];
    f16x8 qh1 = *(const f16x8*)&qh[tq * 1536 + h * 64 + 32 + quad * 8];
    f16x8 ql0 = *(const f16x8*)&ql[tq * 1536 + h * 64 + quad * 8];
    f16x8 ql1 = *(const f16x8*)&ql[tq * 1536 + h * 64 + 32 + quad * 8];

    f32x4 ao[4] = {}, ao2[4] = {};
    float m_i[4] = {-INFINITY, -INFINITY, -INFINITY, -INFINITY};
    float l_i[4] = {0.f, 0.f, 0.f, 0.f};

    const f16* kbh = qh + (size_t)b * 1024 * 1536 + 512 + h * 64;
    const f16* kbl = ql + (size_t)b * 1024 * 1536 + 512 + h * 64;
    const f16* vbh = vth + (size_t)bh * 64 * 1024;
    const f16* vbl = vtl + (size_t)bh * 64 * 1024;

    const int c0 = tid,       r0 = c0 >> 3, g0 = ((c0 & 7) ^ (r0 & 7)) * 8;
    const int c1 = tid + 256, r1 = c1 >> 3, g1 = ((c1 & 7) ^ (r1 & 7)) * 8;
    const int ko0 = r0 * 1536 + g0, ko1 = r1 * 1536 + g1;   // K: row stride 1536 f16
    const int vo0 = r0 * 1024 + g0, vo1 = r1 * 1024 + g1;   // V^T: row stride 1024 f16

    for (int kv0 = 0; kv0 < 1024; kv0 += 64) {
        __syncthreads();   // previous iteration's LDS reads complete before overwrite
        {
            const size_t kadv = (size_t)kv0 * 1536;
            gload_lds16(kbh + kadv + ko0, &Ksh[c0 * 8]);
            gload_lds16(kbh + kadv + ko1, &Ksh[c1 * 8]);
            gload_lds16(kbl + kadv + ko0, &Ksl[c0 * 8]);
            gload_lds16(kbl + kadv + ko1, &Ksl[c1 * 8]);
            gload_lds16(vbh + kv0 + vo0, &Vsh[c0 * 8]);
            gload_lds16(vbh + kv0 + vo1, &Vsh[c1 * 8]);
            gload_lds16(vbl + kv0 + vo0, &Vsl[c0 * 8]);
            gload_lds16(vbl + kv0 + vo1, &Vsl[c1 * 8]);
        }
        __syncthreads();   // drains vmcnt(0): tiles landed for all waves

        f32x4 sa[4] = {}, sa2[4] = {};
        const int sw = l15 & 7;
#pragma unroll
        for (int ni = 0; ni < 4; ni++) {
            const int kb = (ni*16 + l15) * 64;
            f16x8 kh0 = *(const f16x8*)&Ksh[kb + ((quad       ^ sw) << 3)];
            f16x8 kh1 = *(const f16x8*)&Ksh[kb + (((quad + 4) ^ sw) << 3)];
            f16x8 kl0 = *(const f16x8*)&Ksl[kb + ((quad       ^ sw) << 3)];
            f16x8 kl1 = *(const f16x8*)&Ksl[kb + (((quad + 4) ^ sw) << 3)];
            sa[ni]  = __builtin_amdgcn_mfma_f32_16x16x32_f16(qh0, kh0, sa[ni], 0, 0, 0);
            sa[ni]  = __builtin_amdgcn_mfma_f32_16x16x32_f16(qh1, kh1, sa[ni], 0, 0, 0);
            sa2[ni] = __builtin_amdgcn_mfma_f32_16x16x32_f16(qh0, kl0, sa2[ni], 0, 0, 0);
            sa2[ni] = __builtin_amdgcn_mfma_f32_16x16x32_f16(qh1, kl1, sa2[ni], 0, 0, 0);
            sa2[ni] = __builtin_amdgcn_mfma_f32_16x16x32_f16(ql0, kh0, sa2[ni], 0, 0, 0);
            sa2[ni] = __builtin_amdgcn_mfma_f32_16x16x32_f16(ql1, kh1, sa2[ni], 0, 0, 0);
        }
        float alpha[4];
#pragma unroll
        for (int r = 0; r < 4; r++) {
            float s0 = (sa[0][r] + sa2[0][r]*RCP2048) * 0.125f;
            float s1 = (sa[1][r] + sa2[1][r]*RCP2048) * 0.125f;
            float s2 = (sa[2][r] + sa2[2][r]*RCP2048) * 0.125f;
            float s3 = (sa[3][r] + sa2[3][r]*RCP2048) * 0.125f;
            float mx = fmaxf(fmaxf(s0, s1), fmaxf(s2, s3));
#pragma unroll
            for (int msk = 1; msk < 16; msk <<= 1) mx = fmaxf(mx, __shfl_xor(mx, msk));
            float mnew = fmaxf(m_i[r], mx);
            alpha[r] = __expf(m_i[r] - mnew);
            float p0 = __expf(s0 - mnew), p1 = __expf(s1 - mnew);
            float p2 = __expf(s2 - mnew), p3 = __expf(s3 - mnew);
            sa[0][r] = p0; sa[1][r] = p1; sa[2][r] = p2; sa[3][r] = p3;
            float sum = p0 + p1 + p2 + p3;
#pragma unroll
            for (int msk = 1; msk < 16; msk <<= 1) sum += __shfl_xor(sum, msk);
            l_i[r] = l_i[r] * alpha[r] + sum;
            m_i[r] = mnew;
        }
#pragma unroll
        for (int ni = 0; ni < 4; ni++)
#pragma unroll
            for (int r = 0; r < 4; r++) {
                f16 hh, ll; split_f(sa[ni][r], &hh, &ll);
                Ph[wave][quad*4 + r][ni*16 + l15] = hh;
                Pl[wave][quad*4 + r][ni*16 + l15] = ll;
            }
#pragma unroll
        for (int di = 0; di < 4; di++)
#pragma unroll
            for (int r = 0; r < 4; r++) { ao[di][r] *= alpha[r]; ao2[di][r] *= alpha[r]; }
        f16x8 pfh0 = *(const f16x8*)&Ph[wave][l15][quad * 8];
        f16x8 pfh1 = *(const f16x8*)&Ph[wave][l15][32 + quad * 8];
        f16x8 pfl0 = *(const f16x8*)&Pl[wave][l15][quad * 8];
        f16x8 pfl1 = *(const f16x8*)&Pl[wave][l15][32 + quad * 8];
#pragma unroll
        for (int di = 0; di < 4; di++) {
            const int vb = (di*16 + l15) * 64;
            f16x8 vh0 = *(const f16x8*)&Vsh[vb + ((quad       ^ sw) << 3)];
            f16x8 vh1 = *(const f16x8*)&Vsh[vb + (((quad + 4) ^ sw) << 3)];
            f16x8 vl0 = *(const f16x8*)&Vsl[vb + ((quad       ^ sw) << 3)];
            f16x8 vl1 = *(const f16x8*)&Vsl[vb + (((quad + 4) ^ sw) << 3)];
            ao[di]  = __builtin_amdgcn_mfma_f32_16x16x32_f16(pfh0, vh0, ao[di], 0, 0, 0);
            ao[di]  = __builtin_amdgcn_mfma_f32_16x16x32_f16(pfh1, vh1, ao[di], 0, 0, 0);
            ao2[di] = __builtin_amdgcn_mfma_f32_16x16x32_f16(pfh0, vl0, ao2[di], 0, 0, 0);
            ao2[di] = __builtin_amdgcn_mfma_f32_16x16x32_f16(pfh1, vl1, ao2[di], 0, 0, 0);
            ao2[di] = __builtin_amdgcn_mfma_f32_16x16x32_f16(pfl0, vh0, ao2[di], 0, 0, 0);
            ao2[di] = __builtin_amdgcn_mfma_f32_16x16x32_f16(pfl1, vh1, ao2[di], 0, 0, 0);
        }
    }
#pragma unroll
    for (int di = 0; di < 4; di++) {
#pragma unroll
        for (int r = 0; r < 4; r++) {
            size_t t = (size_t)b * 1024 + qt * 64 + wave * 16 + quad * 4 + r;
            float v = (ao[di][r] + ao2[di][r] * RCP2048) / l_i[r];
            f16 hh, ll; split_f(v, &hh, &ll);
            oh[t * 512 + h * 64 + di * 16 + l15] = hh;
            ol[t * 512 + h * 64 + di * 16 + l15] = ll;
        }
    }
}

// ---------------- gating (fp32, no atomics) ----------------
__global__ __launch_bounds__(64) void gating_k(const float* __restrict__ xn, const float* __restrict__ wg,
                                               int* __restrict__ top_i, float* __restrict__ top_g) {
    int t = blockIdx.x, lane = threadIdx.x;
    const float* xr = xn + (size_t)t * 512;
    float acc[8] = {};
#pragma unroll
    for (int i = 0; i < 8; i++) {
        int d = lane + i*64;
        float xv = xr[d];
        const float* wrow = wg + (size_t)d * 8;
#pragma unroll
        for (int e = 0; e < 8; e++) acc[e] += xv * wrow[e];
    }
#pragma unroll
    for (int e = 0; e < 8; e++)
#pragma unroll
        for (int m = 32; m; m >>= 1) acc[e] += __shfl_xor(acc[e], m);
    if (lane == 0) {
        int e0 = 0; float v0 = acc[0];
        for (int e = 1; e < 8; e++) if (acc[e] > v0) { v0 = acc[e]; e0 = e; }
        int e1 = -1; float v1 = -INFINITY;
        for (int e = 0; e < 8; e++) if (e != e0 && acc[e] > v1) { v1 = acc[e]; e1 = e; }
        float g0 = 1.f / (1.f + expf(v1 - v0));
        top_i[2*t] = e0; top_i[2*t + 1] = e1;
        top_g[2*t] = g0; top_g[2*t + 1] = 1.f - g0;
    }
}

// ---------------- fused routing: histogram + offsets in one single-block kernel ----------------
__global__ __launch_bounds__(1024) void route_k(const int* __restrict__ top_i, int* __restrict__ counts,
                                                int* __restrict__ offs, int* __restrict__ cursor) {
    __shared__ int lc[8];
    int tid = threadIdx.x;
    if (tid < 8) lc[tid] = 0;
    __syncthreads();
    const int4* p = (const int4*)top_i;          // 16384 ints = 4096 int4
#pragma unroll
    for (int i = 0; i < 4; i++) {
        int4 v = p[tid + i*1024];
        atomicAdd(&lc[v.x], 1); atomicAdd(&lc[v.y], 1);
        atomicAdd(&lc[v.z], 1); atomicAdd(&lc[v.w], 1);
    }
    __syncthreads();
    if (tid == 0) {
        int o = 0;
        for (int e = 0; e < 8; e++) { int c = lc[e]; counts[e] = c; offs[e] = o; cursor[e] = o; o += c; }
    }
}

// ---------------- scatter: per-block LDS ranks + 8 global atomics per block ----------------
__global__ __launch_bounds__(256) void scatter_k(const int* __restrict__ top_i, int* __restrict__ cursor,
                                                 int* __restrict__ assign_token, int* __restrict__ assign_slot) {
    __shared__ int lcnt[8];
    __shared__ int base[8];
    int tid = threadIdx.x;
    int t = blockIdx.x * 256 + tid;
    if (tid < 8) lcnt[tid] = 0;
    __syncthreads();
    int e0 = top_i[2*t], e1 = top_i[2*t + 1];
    int r0 = atomicAdd(&lcnt[e0], 1);
    int r1 = atomicAdd(&lcnt[e1], 1);
    __syncthreads();
    if (tid < 8) base[tid] = atomicAdd(&cursor[tid], lcnt[tid]);
    __syncthreads();
    int p0 = base[e0] + r0, p1 = base[e1] + r1;
    assign_token[p0] = t; assign_slot[2*t]     = p0;
    assign_token[p1] = t; assign_slot[2*t + 1] = p1;
}

__global__ __launch_bounds__(64) void gather2_k(const f16* __restrict__ xh, const f16* __restrict__ xl,
                                                const int* __restrict__ assign_token,
                                                f16* __restrict__ oh, f16* __restrict__ ol) {
    int a = blockIdx.x, lane = threadIdx.x;
    int t = assign_token[a];
    ((uint4*)(oh + (size_t)a * 512))[lane] = ((const uint4*)(xh + (size_t)t * 512))[lane];
    ((uint4*)(ol + (size_t)a * 512))[lane] = ((const uint4*)(xl + (size_t)t * 512))[lane];
}

__global__ __launch_bounds__(64) void combine_k(float* __restrict__ x, const float* __restrict__ y,
                                                const int* __restrict__ assign_slot, const float* __restrict__ top_g) {
    int t = blockIdx.x, lane = threadIdx.x;
    int p0 = assign_slot[2*t], p1 = assign_slot[2*t + 1];
    float g0 = top_g[2*t], g1 = top_g[2*t + 1];
    float4* xr = (float4*)(x + (size_t)t * 512);
    const float4* y0 = (const float4*)(y + (size_t)p0 * 512);
    const float4* y1 = (const float4*)(y + (size_t)p1 * 512);
#pragma unroll
    for (int i = 0; i < 2; i++) {
        int idx = lane + i * 64;
        float4 a = xr[idx], c0 = y0[idx], c1 = y1[idx];
        a.x += g0*c0.x + g1*c1.x; a.y += g0*c0.y + g1*c1.y;
        a.z += g0*c0.z + g1*c1.z; a.w += g0*c0.w + g1*c1.w;
        xr[idx] = a;
    }
}

extern "C" void kernel_launch(void* const* d_in, const int* in_sizes, int n_in,
                              void* d_out, int out_size, void* d_ws, size_t ws_size,
                              hipStream_t stream) {
    const float* x_in = (const float*)d_in[0];
    const float* ln1w = (const float*)d_in[1];
    const float* ln1b = (const float*)d_in[2];
    const float* qkvw = (const float*)d_in[3];
    const float* outw = (const float*)d_in[4];
    const float* outb = (const float*)d_in[5];
    const float* ln2w = (const float*)d_in[6];
    const float* ln2b = (const float*)d_in[7];
    const float* wg   = (const float*)d_in[8];
    const float* ew1  = (const float*)d_in[9];
    const float* eb1  = (const float*)d_in[10];
    const float* ew2  = (const float*)d_in[11];
    const float* eb2  = (const float*)d_in[12];
    const float* flnw = (const float*)d_in[13];
    const float* flnb = (const float*)d_in[14];

    float* x = (float*)d_out;                         // residual [8192,512] f32

    char* ws = (char*)d_ws;
    float* xn32  = (float*)(ws + 0);                  // 16 MB (dead after gating)
    f16*   xnh   = (f16*)(ws + 16*MB);                //  8 MB (dead after gather2)
    f16*   xnl   = (f16*)(ws + 24*MB);                //  8 MB
    f16*   qkTh  = (f16*)(ws + 32*MB);                //  1.5 MB
    f16*   qkTl  = (f16*)(ws + 34*MB);
    f16*   outTh = (f16*)(ws + 36*MB);                //  0.5 MB
    f16*   outTl = (f16*)(ws + 37*MB);
    f16*   w1Th  = (f16*)(ws + 38*MB);                // 16 MB [8][2048][512]
    f16*   w1Tl  = (f16*)(ws + 54*MB);
    f16*   w2Th  = (f16*)(ws + 70*MB);                // 16 MB [8][512][2048]
    f16*   w2Tl  = (f16*)(ws + 86*MB);
    char*  S     = ws + 102*MB;                       // 96 MB scratch
    // attn phase
    f16*   qbh   = (f16*)(S + 0);                     // 24 MB [8192,1536]
    f16*   qbl   = (f16*)(S + 24*MB);
    f16*   vth   = (f16*)(S + 48*MB);                 //  8 MB [64][64][1024]
    f16*   vtl   = (f16*)(S + 56*MB);
    f16*   obh   = (f16*)(S + 64*MB);                 //  8 MB [8192,512]
    f16*   obl   = (f16*)(S + 72*MB);
    // moe phase (reuses S + dead ws+0..32 region)
    f16*   xeh   = (f16*)(S + 0);                     // 16 MB [16384,512]
    f16*   xel   = (f16*)(S + 16*MB);
    f16*   hbh   = (f16*)(S + 32*MB);                 // 32 MB [16384,1024] per N-slice
    f16*   hbl   = (f16*)(S + 64*MB);                 // 32 MB
    float* ybuf  = (float*)(ws + 0);                  // 32 MB [16384,512] (over xn32/xnh/xnl, dead by then)
    char*  SM    = ws + 198*MB;
    int*   top_i        = (int*)(SM + 0);
    float* top_g        = (float*)(SM + 65536);
    int*   assign_token = (int*)(SM + 131072);
    int*   assign_slot  = (int*)(SM + 196608);
    int*   counts       = (int*)(SM + 262144);
    int*   offs         = (int*)(SM + 262400);
    int*   cursor       = (int*)(SM + 262656);

    hipMemcpyAsync(x, x_in, (size_t)8192 * 512 * 4, hipMemcpyDeviceToDevice, stream);

    dim3 tb(32, 8);
    for (int l = 0; l < 4; l++) {
        const float* qkvw_l = qkvw + (size_t)l * 512 * 1536;
        const float* outw_l = outw + (size_t)l * 512 * 512;
        const float* ew1_l  = ew1  + (size_t)l * 8 * 512 * 2048;
        const float* ew2_l  = ew2  + (size_t)l * 8 * 2048 * 512;
        const float* eb1_l  = eb1  + (size_t)l * 8 * 2048;
        const float* eb2_l  = eb2  + (size_t)l * 8 * 512;

        // weight prep: transpose + split to fp16 hi/lo, [N,K] layout
        transpose_split_k<<<dim3(48, 16, 1), tb, 0, stream>>>(qkvw_l, qkTh, qkTl, 512, 1536, 0, 0);
        transpose_split_k<<<dim3(16, 16, 1), tb, 0, stream>>>(outw_l, outTh, outTl, 512, 512, 0, 0);
        transpose_split_k<<<dim3(64, 16, 8), tb, 0, stream>>>(ew1_l, w1Th, w1Tl, 512, 2048,
                                                              (long)512*2048, (long)512*2048);
        transpose_split_k<<<dim3(16, 64, 8), tb, 0, stream>>>(ew2_l, w2Th, w2Tl, 2048, 512,
                                                              (long)2048*512, (long)2048*512);

        // ---- attention ----
        ln_split_k<0><<<8192, 256, 0, stream>>>(x, ln1w + l*512, ln1b + l*512, nullptr, xnh, xnl);
        gemm_sp<0><<<768, 256, 0, stream>>>(xnh, xnl, 512, qkTh, qkTl, 512, nullptr,
                                            qbh, qbl, 1536, 8192, 512, 64, 12,
                                            nullptr, nullptr, 0, 0);
        transpose_v_k<<<dim3(32, 2, 64), tb, 0, stream>>>(qbh, qbl, vth, vtl);
        attn_sp<<<dim3(16, 64), 256, 0, stream>>>(qbh, qbl, vth, vtl, obh, obl);
        gemm_sp<1><<<256, 256, 0, stream>>>(obh, obl, 512, outTh, outTl, 512, outb + l*512,
                                            x, nullptr, 512, 8192, 512, 64, 4,
                                            nullptr, nullptr, 0, 0);

        // ---- MoE ----
        ln_split_k<1><<<8192, 256, 0, stream>>>(x, ln2w + l*512, ln2b + l*512, xn32, xnh, xnl);
        gating_k<<<8192, 64, 0, stream>>>(xn32, wg + (size_t)l*512*8, top_i, top_g);
        route_k<<<1, 1024, 0, stream>>>(top_i, counts, offs, cursor);
        scatter_k<<<32, 256, 0, stream>>>(top_i, cursor, assign_token, assign_slot);
        gather2_k<<<16384, 64, 0, stream>>>(xnh, xnl, assign_token, xeh, xel);

        for (int s = 0; s < 2; s++) {
            const f16* b1h = w1Th + (size_t)s * 1024 * 512;   // rows s*1024.. of [2048,512]
            const f16* b1l = w1Tl + (size_t)s * 1024 * 512;
            const f16* b2h = w2Th + (size_t)s * 1024;         // k-cols s*1024.. of [512,2048]
            const f16* b2l = w2Tl + (size_t)s * 1024;
            // h = gelu(xe @ w1_slice + b1): M=16384 (per-expert), N=1024, K=512
            gemm_sp<2><<<64*8*8, 256, 0, stream>>>(xeh, xel, 512, b1h, b1l, 512, eb1_l + s*1024,
                                                   hbh, hbl, 1024, 0, 512, 64, 8,
                                                   counts, offs, (long)2048*512, 2048);
            // y (+)= h @ w2_kslice: M=16384, N=512, K=1024
            if (s == 0)
                gemm_sp<3><<<64*4*8, 256, 0, stream>>>(hbh, hbl, 1024, b2h, b2l, 2048, eb2_l,
                                                       ybuf, nullptr, 512, 0, 1024, 64, 4,
                                                       counts, offs, (long)512*2048, 512);
            else
                gemm_sp<4><<<64*4*8, 256, 0, stream>>>(hbh, hbl, 1024, b2h, b2l, 2048, nullptr,
                                                       ybuf, nullptr, 512, 0, 1024, 64, 4,
                                                       counts, offs, (long)512*2048, 512);
        }
        combine_k<<<8192, 64, 0, stream>>>(x, ybuf, assign_slot, top_g);
    }
    ln_k<<<8192, 256, 0, stream>>>(x, flnw, flnb, x);
}